// Round 8
// baseline (295.127 us; speedup 1.0000x reference)
//
#include <hip/hip_runtime.h>
#include <hip/hip_bf16.h>
#include <math.h>

#define Bn 16
#define Tn 128
#define Sn 128
#define Dn 512
#define Hn 100
#define TT 4

typedef short short8 __attribute__((ext_vector_type(8)));
typedef float f32x4 __attribute__((ext_vector_type(4)));
typedef unsigned short ushort4v __attribute__((ext_vector_type(4)));

__device__ __forceinline__ float softplus_f(float x) {
    return fmaxf(x, 0.0f) + __logf(1.0f + __expf(-fabsf(x)));
}
__device__ __forceinline__ unsigned short f2bf(float f) {
    unsigned u = __float_as_uint(f);
    unsigned r = u + 0x7FFFu + ((u >> 16) & 1u);
    return (unsigned short)(r >> 16);
}
__device__ __forceinline__ float bf2f(unsigned short h) {
    return __uint_as_float(((unsigned)h) << 16);
}
__device__ __forceinline__ unsigned pkrn(float a, float b) {
    __hip_bfloat162 h = __float22bfloat162_rn(float2{a, b});
    return *reinterpret_cast<unsigned*>(&h);
}
struct BfPair { unsigned short h, l; };
__device__ __forceinline__ BfPair split2(float x) {
    BfPair p;
    p.h = f2bf(x);
    p.l = f2bf(x - bf2f(p.h));
    return p;
}

// ---------------------------------------------------------------------------
// Fused conversion + mem transpose (blocks >= 2930 do the transpose).
// ---------------------------------------------------------------------------
__global__ __launch_bounds__(256)
void conv_trans(const float* __restrict__ input, const float* __restrict__ mem,
                const float* __restrict__ W_in, const float* __restrict__ W1,
                const float* __restrict__ W_out, const float* __restrict__ W2,
                unsigned short* __restrict__ inh, unsigned short* __restrict__ inl,
                unsigned short* __restrict__ memh, unsigned short* __restrict__ meml,
                unsigned short* __restrict__ winh, unsigned short* __restrict__ winl,
                unsigned short* __restrict__ w1b, unsigned short* __restrict__ woutb,
                unsigned short* __restrict__ w2b, unsigned short* __restrict__ concatb,
                unsigned short* __restrict__ memTb)
{
    __shared__ float tile[64][65];
    const int bx = blockIdx.x;
    if (bx >= 2930) {
        const int b2x = bx - 2930;
        const int d0 = (b2x & 7) * 64, s0 = ((b2x >> 3) & 1) * 64, b = b2x >> 4;
        const int tid = threadIdx.x;
        const int r = tid >> 2, cb = (tid & 3) * 16;
        const float* src = mem + ((long)b * Sn + s0 + r) * Dn + d0 + cb;
        #pragma unroll
        for (int j = 0; j < 4; ++j) {
            float4 v = *(const float4*)&src[j * 4];
            tile[r][cb + j * 4 + 0] = v.x;
            tile[r][cb + j * 4 + 1] = v.y;
            tile[r][cb + j * 4 + 2] = v.z;
            tile[r][cb + j * 4 + 3] = v.w;
        }
        __syncthreads();
        unsigned short* dst = memTb + ((long)b * Dn + d0 + r) * Sn + s0 + cb;
        #pragma unroll
        for (int j = 0; j < 4; ++j) {
            ushort4v q;
            q.x = f2bf(tile[cb + j * 4 + 0][r]);
            q.y = f2bf(tile[cb + j * 4 + 1][r]);
            q.z = f2bf(tile[cb + j * 4 + 2][r]);
            q.w = f2bf(tile[cb + j * 4 + 3][r]);
            *(ushort4v*)&dst[j * 4] = q;
        }
        return;
    }
    long gid = (long)bx * 1024 + (long)threadIdx.x * 4;
    if (gid < 1048576) {
        float4 v = *(const float4*)&input[gid];
        BfPair a = split2(v.x), b = split2(v.y), c = split2(v.z), d = split2(v.w);
        ushort4v h = {a.h, b.h, c.h, d.h};
        ushort4v l = {a.l, b.l, c.l, d.l};
        *(ushort4v*)&inh[gid] = h;
        *(ushort4v*)&inl[gid] = l;
        long row = gid >> 9; int col = (int)(gid & 511);
        *(ushort4v*)&concatb[row * 1024 + 512 + col] = h;
    } else if (gid < 2097152) {
        long e = gid - 1048576;
        float4 v = *(const float4*)&mem[e];
        BfPair a = split2(v.x), b = split2(v.y), c = split2(v.z), d = split2(v.w);
        ushort4v h = {a.h, b.h, c.h, d.h};
        ushort4v l = {a.l, b.l, c.l, d.l};
        *(ushort4v*)&memh[e] = h;
        *(ushort4v*)&meml[e] = l;
    } else if (gid < 2359296) {
        long e = gid - 2097152;
        float4 v = *(const float4*)&W_in[e];
        BfPair a = split2(v.x), b = split2(v.y), c = split2(v.z), d = split2(v.w);
        ushort4v h = {a.h, b.h, c.h, d.h};
        ushort4v l = {a.l, b.l, c.l, d.l};
        *(ushort4v*)&winh[e] = h;
        *(ushort4v*)&winl[e] = l;
    } else if (gid < 2461696) {
        long e = gid - 2359296;
        float4 v = *(const float4*)&W1[e];
        ushort4v h = {f2bf(v.x), f2bf(v.y), f2bf(v.z), f2bf(v.w)};
        *(ushort4v*)&w1b[e] = h;
    } else if (gid < 2985984) {
        long e = gid - 2461696;
        float4 v = *(const float4*)&W_out[e];
        ushort4v h = {f2bf(v.x), f2bf(v.y), f2bf(v.z), f2bf(v.w)};
        *(ushort4v*)&woutb[e] = h;
    } else {
        long e = gid - 2985984;           // [112][128] padded W2
        int n = (int)(e >> 7), k = (int)(e & 127);
        ushort4v h;
        #pragma unroll
        for (int j = 0; j < 4; ++j) {
            int kj = k + j;
            float val = (n < Hn && kj < Hn) ? W2[n * Hn + kj] : 0.0f;
            h[j] = f2bf(val);
        }
        *(ushort4v*)&w2b[n * 128 + k] = h;
    }
}

// ---------------------------------------------------------------------------
// 64x64-tile bf16 MFMA GEMM body (NT). BK=64, 256 thr = 4 waves (2x2).
// ---------------------------------------------------------------------------
template<int SPLIT, int EPI, int KSPLIT, int BSEL>
__device__ __forceinline__
void gemm_body(int bx, int by, int bz_in, int upperThresh,
               const unsigned short* __restrict__ Ah, const unsigned short* __restrict__ Al,
               const unsigned short* __restrict__ Bh, const unsigned short* __restrict__ Bl,
               float* __restrict__ C, unsigned short* __restrict__ Cb,
               unsigned short* __restrict__ Cb2, const float* __restrict__ bias,
               int N, int K, int lda, int ldb, int ldc,
               long sA, long sB, long sC, long sKC,
               unsigned short* As_, unsigned short* Bs_)
{
    unsigned short* Asl = As_ + 4096;
    unsigned short* Bsl = Bs_ + 4096;

    const int tid = threadIdx.x;
    const int n0 = bx * 64;
    const long m0 = (long)by * 64;
    int bz = bz_in, kh = 0;
    if (KSPLIT) { bz = bz_in & 15; kh = bz_in >> 4; }
    Ah += (long)bz * sA;
    Bh += (long)bz * sB;
    if (SPLIT) { Al += (long)bz * sA; Bl += (long)bz * sB; }
    const bool upperB = BSEL && (by >= upperThresh);
    if (upperB) Bh += BSEL;

    const int kbeg = KSPLIT ? kh * (K / KSPLIT) : 0;
    const int kend = KSPLIT ? kbeg + (K / KSPLIT) : K;

    const int wid = tid >> 6, lane = tid & 63;
    const int lm = lane & 15, lq = lane >> 4;
    const int wm = wid & 1, wn = wid >> 1;

    const int sr = tid >> 2;
    const int sc = (tid & 3) * 2;
    const bool bok = (n0 + sr) < N;

    f32x4 acc[2][2];
    #pragma unroll
    for (int i = 0; i < 2; ++i)
        #pragma unroll
        for (int j = 0; j < 2; ++j)
            acc[i][j] = (f32x4){0.f, 0.f, 0.f, 0.f};

    for (int k0 = kbeg; k0 < kend; k0 += 64) {
        __syncthreads();
        #pragma unroll
        for (int i = 0; i < 2; ++i) {
            int c = sc + i, p = c ^ (sr & 7);
            *(short8*)&As_[sr * 64 + p * 8] =
                *(const short8*)&Ah[(m0 + sr) * lda + k0 + c * 8];
            if (SPLIT)
                *(short8*)&Asl[sr * 64 + p * 8] =
                    *(const short8*)&Al[(m0 + sr) * lda + k0 + c * 8];
        }
        #pragma unroll
        for (int i = 0; i < 2; ++i) {
            int c = sc + i, p = c ^ (sr & 7);
            short8 v = {0, 0, 0, 0, 0, 0, 0, 0};
            short8 vl = {0, 0, 0, 0, 0, 0, 0, 0};
            if (bok) {
                v = *(const short8*)&Bh[(long)(n0 + sr) * ldb + k0 + c * 8];
                if (SPLIT) vl = *(const short8*)&Bl[(long)(n0 + sr) * ldb + k0 + c * 8];
            }
            *(short8*)&Bs_[sr * 64 + p * 8] = v;
            if (SPLIT) *(short8*)&Bsl[sr * 64 + p * 8] = vl;
        }
        __syncthreads();
        #pragma unroll
        for (int kst = 0; kst < 2; ++kst) {
            short8 a[2], b[2], a2[2], b2r[2];
            const int pp = (kst * 4 + lq) ^ (lm & 7);
            #pragma unroll
            for (int mt = 0; mt < 2; ++mt) {
                int row = wm * 32 + mt * 16 + lm;
                a[mt] = *(const short8*)&As_[row * 64 + pp * 8];
                if (SPLIT) a2[mt] = *(const short8*)&Asl[row * 64 + pp * 8];
            }
            #pragma unroll
            for (int nt = 0; nt < 2; ++nt) {
                int row = wn * 32 + nt * 16 + lm;
                b[nt] = *(const short8*)&Bs_[row * 64 + pp * 8];
                if (SPLIT) b2r[nt] = *(const short8*)&Bsl[row * 64 + pp * 8];
            }
            #pragma unroll
            for (int mt = 0; mt < 2; ++mt)
                #pragma unroll
                for (int nt = 0; nt < 2; ++nt) {
                    if (SPLIT) {
                        acc[mt][nt] = __builtin_amdgcn_mfma_f32_16x16x32_bf16(
                            a2[mt], b[nt], acc[mt][nt], 0, 0, 0);
                        acc[mt][nt] = __builtin_amdgcn_mfma_f32_16x16x32_bf16(
                            a[mt], b2r[nt], acc[mt][nt], 0, 0, 0);
                    }
                    acc[mt][nt] = __builtin_amdgcn_mfma_f32_16x16x32_bf16(
                        a[mt], b[nt], acc[mt][nt], 0, 0, 0);
                }
        }
    }

    #pragma unroll
    for (int mt = 0; mt < 2; ++mt)
        #pragma unroll
        for (int nt = 0; nt < 2; ++nt)
            #pragma unroll
            for (int r = 0; r < 4; ++r) {
                long m = m0 + wm * 32 + mt * 16 + lq * 4 + r;
                int n = n0 + wn * 32 + nt * 16 + lm;
                float v = acc[mt][nt][r];
                if (EPI == 0) {
                    if (n < N)
                        C[(long)bz * sC + (long)kh * sKC + m * ldc + n] = v;
                } else if (EPI == 1) {
                    unsigned short h = f2bf(v);
                    Cb[m * ldc + n] = h;
                    Cb2[m * ldc + n] = f2bf(v - bf2f(h));
                } else if (EPI == 2) {
                    long bb = m >> 7, tt = m & 127;
                    C[tt * (Bn * Dn) + bb * Dn + n] = tanhf(v);
                } else if (EPI == 3) {
                    Cb[(long)bz * sC + m * ldc + n] = f2bf(v);
                } else {
                    float bb = (!upperB && n < Hn) ? bias[n] : 0.f;
                    C[m * ldc + n] = v + bb;
                }
            }
}

template<int SPLIT, int EPI, int KSPLIT, int BSEL>
__global__ __launch_bounds__(256)
void mfma_gemm3(const unsigned short* __restrict__ Ah, const unsigned short* __restrict__ Al,
                const unsigned short* __restrict__ Bh, const unsigned short* __restrict__ Bl,
                float* __restrict__ C, unsigned short* __restrict__ Cb,
                unsigned short* __restrict__ Cb2, const float* __restrict__ bias,
                int N, int K, int lda, int ldb, int ldc,
                long sA, long sB, long sC, long sKC)
{
    __shared__ __align__(16) unsigned short As_[(SPLIT ? 2 : 1) * 4096];
    __shared__ __align__(16) unsigned short Bs_[(SPLIT ? 2 : 1) * 4096];
    gemm_body<SPLIT, EPI, KSPLIT, BSEL>(blockIdx.x, blockIdx.y, blockIdx.z,
        (int)(gridDim.y >> 1), Ah, Al, Bh, Bl, C, Cb, Cb2, bias,
        N, K, lda, ldb, ldc, sA, sB, sC, sKC, As_, Bs_);
}

// ---------------------------------------------------------------------------
// Merged independent GEMMs: blocks 0..255 = ht (split), 256..383 = pt+ps.
// ---------------------------------------------------------------------------
__global__ __launch_bounds__(256)
void gemm_ht_ptps(const unsigned short* __restrict__ inh, const unsigned short* __restrict__ inl,
                  const unsigned short* __restrict__ winh, const unsigned short* __restrict__ winl,
                  unsigned short* __restrict__ hth, unsigned short* __restrict__ htl,
                  const unsigned short* __restrict__ w1b, float* __restrict__ ptps,
                  const float* __restrict__ b1)
{
    __shared__ __align__(16) unsigned short As_[8192];
    __shared__ __align__(16) unsigned short Bs_[8192];
    const int id = blockIdx.x;
    if (id < 256) {
        gemm_body<1, 1, 0, 0>(id & 7, id >> 3, 0, 0,
            inh, inl, winh, winl, nullptr, hth, htl, nullptr,
            Dn, Dn, Dn, Dn, Dn, 0L, 0L, 0L, 0L, As_, Bs_);
    } else {
        const int j = id - 256;
        gemm_body<0, 4, 0, 512>(j & 1, j >> 1, 0, 32,
            inh, nullptr, w1b, nullptr, ptps, nullptr, nullptr, b1,
            Hn, Dn, Dn, 2 * Dn, 128, 0L, 0L, 0L, 0L, As_, Bs_);
    }
}

// ---------------------------------------------------------------------------
// Standalone fused MLP (register-built h1 as MFMA B-operand).
// Grid (32, 32): bx = t-group of 4, by = b + 16*s_half. 256 thr = 4 waves.
// W2 (A-operand) in swizzled LDS staged once; zero barriers in the t-loop.
// __launch_bounds__(256,4) caps VGPR at 128 -> 4 waves/SIMD.
// ---------------------------------------------------------------------------
__global__ __launch_bounds__(256, 4)
void mlp_mfma5(const float* __restrict__ ptps,
               const unsigned short* __restrict__ w2b,
               const float* __restrict__ b2,
               const float* __restrict__ w_mean, const float* __restrict__ b_mean,
               const float* __restrict__ w_var, const float* __restrict__ b_var,
               float* __restrict__ mean_out, float* __restrict__ var_out)
{
    __shared__ __align__(16) unsigned short w2s[112 * 128];   // 28672 B
    __shared__ float ptl[TT][132];
    __shared__ float wpk[224];
    __shared__ float b2l[112];

    const int tg = blockIdx.x;
    const int b  = blockIdx.y & 15;
    const int s0 = (blockIdx.y >> 4) * 64;
    const int tid = threadIdx.x;

    // stage w2 (swizzled)
    #pragma unroll
    for (int i0 = 0; i0 < 7; ++i0) {
        int i = tid + i0 * 256;
        int r_ = i >> 4, c_ = i & 15;
        *(short8*)&w2s[r_ * 128 + (c_ ^ (r_ & 7)) * 8] = *(const short8*)&w2b[i * 8];
    }
    // stage pt rows (4 x 128)
    #pragma unroll
    for (int j = 0; j < 2; ++j) {
        int i = tid + j * 256;
        int tt = i >> 7, c = i & 127;
        ptl[tt][c] = ptps[((long)b * Tn + tg * TT + tt) * 128 + c];
    }
    // stage padded wm/wv (interleaved) and b2
    if (tid < 224) {
        int g = tid >> 1;
        wpk[tid] = (g < Hn) ? ((tid & 1) ? w_var[g] : w_mean[g]) : 0.f;
    }
    if (tid < 112) b2l[tid] = (tid < Hn) ? b2[tid] : 0.f;

    const int wid = tid >> 6, lane = tid & 63;
    const int lm = lane & 15, lq = lane >> 4;
    const int s = s0 + wid * 16 + lm;

    // ps slice -> registers (lane's B-fragment source), once per block
    float psreg[4][8];
    {
        const float* psrow = ptps + (long)(2048 + b * Sn + s) * 128;
        #pragma unroll
        for (int ks = 0; ks < 4; ++ks) {
            *(float4*)&psreg[ks][0] = *(const float4*)&psrow[ks * 32 + lq * 8];
            *(float4*)&psreg[ks][4] = *(const float4*)&psrow[ks * 32 + lq * 8 + 4];
        }
    }
    const float bm = b_mean[0], bv = b_var[0];
    __syncthreads();

    for (int t = 0; t < TT; ++t) {
        // B-fragments: h1[s = lm][k = lq*8+j] in registers
        short8 hf[4];
        #pragma unroll
        for (int ks = 0; ks < 4; ++ks) {
            float4 pa = *(const float4*)&ptl[t][ks * 32 + lq * 8];
            float4 pb = *(const float4*)&ptl[t][ks * 32 + lq * 8 + 4];
            float x0 = softplus_f(psreg[ks][0] + pa.x);
            float x1 = softplus_f(psreg[ks][1] + pa.y);
            float x2 = softplus_f(psreg[ks][2] + pa.z);
            float x3 = softplus_f(psreg[ks][3] + pa.w);
            float x4 = softplus_f(psreg[ks][4] + pb.x);
            float x5 = softplus_f(psreg[ks][5] + pb.y);
            float x6 = softplus_f(psreg[ks][6] + pb.z);
            float x7 = softplus_f(psreg[ks][7] + pb.w);
            union { uint4 u4; short8 s8; } cv;
            cv.u4.x = pkrn(x0, x1); cv.u4.y = pkrn(x2, x3);
            cv.u4.z = pkrn(x4, x5); cv.u4.w = pkrn(x6, x7);
            hf[ks] = cv.s8;
        }
        // h2^T = W2 @ h1^T : rows = g, cols = s
        f32x4 acc[7];
        #pragma unroll
        for (int j = 0; j < 7; ++j) acc[j] = (f32x4){0.f, 0.f, 0.f, 0.f};
        #pragma unroll
        for (int ks = 0; ks < 4; ++ks) {
            const int p = (ks * 4 + lq) ^ (lm & 7);
            #pragma unroll
            for (int mt = 0; mt < 7; ++mt) {
                short8 w = *(const short8*)&w2s[(mt * 16 + lm) * 128 + p * 8];
                acc[mt] = __builtin_amdgcn_mfma_f32_16x16x32_bf16(w, hf[ks], acc[mt], 0, 0, 0);
            }
        }
        // epilogue: in-lane reduce over 28 g's, butterfly over quads
        float sM = 0.f, sV = 0.f;
        #pragma unroll
        for (int mt = 0; mt < 7; ++mt) {
            const int g0 = mt * 16 + lq * 4;
            float4 bg = *(const float4*)&b2l[g0];
            float4 wa = *(const float4*)&wpk[g0 * 2];
            float4 wb = *(const float4*)&wpk[g0 * 2 + 4];
            float h2;
            h2 = softplus_f(acc[mt][0] + bg.x); sM = fmaf(h2, wa.x, sM); sV = fmaf(h2, wa.y, sV);
            h2 = softplus_f(acc[mt][1] + bg.y); sM = fmaf(h2, wa.z, sM); sV = fmaf(h2, wa.w, sV);
            h2 = softplus_f(acc[mt][2] + bg.z); sM = fmaf(h2, wb.x, sM); sV = fmaf(h2, wb.y, sV);
            h2 = softplus_f(acc[mt][3] + bg.w); sM = fmaf(h2, wb.z, sM); sV = fmaf(h2, wb.w, sV);
        }
        sM += __shfl_xor(sM, 16); sM += __shfl_xor(sM, 32);
        sV += __shfl_xor(sV, 16); sV += __shfl_xor(sV, 32);
        if (lq == 0) {
            const long base = ((long)b * Tn + tg * TT + t) * Sn + s;
            mean_out[base] = softplus_f(sM + bm);
            var_out[base]  = softplus_f(sV + bv);
        }
    }
}

// ---------------------------------------------------------------------------
// Fused softmax + c-GEMM. Grid (8 nt, 2 mt, 16 b), 256 threads.
// ---------------------------------------------------------------------------
__global__ __launch_bounds__(256)
void softmax_c(const float* __restrict__ algn, long kstride,
               const unsigned short* __restrict__ memTb,
               float* __restrict__ av_out, unsigned short* __restrict__ concatb)
{
    __shared__ __align__(16) unsigned short avs[64 * 128];
    __shared__ __align__(16) unsigned short Bs[64 * 128];

    const int ntb = blockIdx.x, mtb = blockIdx.y, b = blockIdx.z;
    const int tid = threadIdx.x;
    const int r = tid >> 2, q = tid & 3;

    // phase 1: softmax rows (4 threads per row, 32 cols each)
    float v[32];
    {
        const float* arow = algn + ((long)b * Tn + mtb * 64 + r) * Sn + q * 32;
        #pragma unroll
        for (int j = 0; j < 8; ++j) {
            float4 a0 = *(const float4*)&arow[j * 4];
            float4 a1 = *(const float4*)&arow[j * 4 + kstride];
            float4 a2 = *(const float4*)&arow[j * 4 + 2 * kstride];
            float4 a3 = *(const float4*)&arow[j * 4 + 3 * kstride];
            v[j * 4 + 0] = a0.x + a1.x + a2.x + a3.x;
            v[j * 4 + 1] = a0.y + a1.y + a2.y + a3.y;
            v[j * 4 + 2] = a0.z + a1.z + a2.z + a3.z;
            v[j * 4 + 3] = a0.w + a1.w + a2.w + a3.w;
        }
    }
    float mx = v[0];
    #pragma unroll
    for (int i = 1; i < 32; ++i) mx = fmaxf(mx, v[i]);
    mx = fmaxf(mx, __shfl_xor(mx, 1));
    mx = fmaxf(mx, __shfl_xor(mx, 2));
    float sum = 0.f;
    #pragma unroll
    for (int i = 0; i < 32; ++i) { v[i] = __expf(v[i] - mx); sum += v[i]; }
    sum += __shfl_xor(sum, 1);
    sum += __shfl_xor(sum, 2);
    const float inv = 1.0f / sum;

    if (ntb == 0) {
        float* dst = av_out + (long)(mtb * 64 + r) * (Bn * Sn) + b * Sn + q * 32;
        #pragma unroll
        for (int j = 0; j < 8; ++j) {
            float4 o = {v[j*4]*inv, v[j*4+1]*inv, v[j*4+2]*inv, v[j*4+3]*inv};
            *(float4*)&dst[j * 4] = o;
        }
    }
    #pragma unroll
    for (int i = 0; i < 4; ++i) {
        int c = q * 4 + i;
        uint4 u;
        u.x = pkrn(v[i*8+0]*inv, v[i*8+1]*inv);
        u.y = pkrn(v[i*8+2]*inv, v[i*8+3]*inv);
        u.z = pkrn(v[i*8+4]*inv, v[i*8+5]*inv);
        u.w = pkrn(v[i*8+6]*inv, v[i*8+7]*inv);
        *(uint4*)&avs[r * 128 + (c ^ (r & 7)) * 8] = u;
    }
    // stage B (memT rows = d)
    #pragma unroll
    for (int j = 0; j < 4; ++j) {
        int idx = tid * 4 + j;
        int rB = idx >> 4, cB = idx & 15;
        *(short8*)&Bs[rB * 128 + (cB ^ (rB & 7)) * 8] =
            *(const short8*)&memTb[((long)b * Dn + ntb * 64 + rB) * Sn + cB * 8];
    }
    __syncthreads();

    // phase 2: c tile = avs @ Bs^T (K=128)
    const int wid = tid >> 6, lane = tid & 63;
    const int lm = lane & 15, lq = lane >> 4;
    const int wm = wid & 1, wn = wid >> 1;

    f32x4 acc[2][2];
    #pragma unroll
    for (int i = 0; i < 2; ++i)
        #pragma unroll
        for (int j = 0; j < 2; ++j) acc[i][j] = (f32x4){0.f, 0.f, 0.f, 0.f};

    #pragma unroll
    for (int kk = 0; kk < 4; ++kk) {
        const int p = (kk * 4 + lq) ^ (lm & 7);
        short8 a0 = *(const short8*)&avs[(wm * 32 + lm) * 128 + p * 8];
        short8 a1 = *(const short8*)&avs[(wm * 32 + 16 + lm) * 128 + p * 8];
        short8 b0 = *(const short8*)&Bs[(wn * 32 + lm) * 128 + p * 8];
        short8 b1 = *(const short8*)&Bs[(wn * 32 + 16 + lm) * 128 + p * 8];
        acc[0][0] = __builtin_amdgcn_mfma_f32_16x16x32_bf16(a0, b0, acc[0][0], 0, 0, 0);
        acc[0][1] = __builtin_amdgcn_mfma_f32_16x16x32_bf16(a0, b1, acc[0][1], 0, 0, 0);
        acc[1][0] = __builtin_amdgcn_mfma_f32_16x16x32_bf16(a1, b0, acc[1][0], 0, 0, 0);
        acc[1][1] = __builtin_amdgcn_mfma_f32_16x16x32_bf16(a1, b1, acc[1][1], 0, 0, 0);
    }
    #pragma unroll
    for (int mt = 0; mt < 2; ++mt)
        #pragma unroll
        for (int nt = 0; nt < 2; ++nt)
            #pragma unroll
            for (int rr = 0; rr < 4; ++rr) {
                long mrow = (long)b * Tn + mtb * 64 + wm * 32 + mt * 16 + lq * 4 + rr;
                int n = ntb * 64 + wn * 32 + nt * 16 + lm;
                concatb[mrow * 1024 + n] = f2bf(acc[mt][nt][rr]);
            }
}

// ---------------------------------------------------------------------------
extern "C" void kernel_launch(void* const* d_in, const int* in_sizes, int n_in,
                              void* d_out, int out_size, void* d_ws, size_t ws_size,
                              hipStream_t stream)
{
    (void)in_sizes; (void)n_in; (void)out_size; (void)ws_size;

    const float* input  = (const float*)d_in[0];
    const float* mem    = (const float*)d_in[1];
    const float* W_in   = (const float*)d_in[2];
    const float* W1     = (const float*)d_in[3];
    const float* b1     = (const float*)d_in[4];
    const float* W2     = (const float*)d_in[5];
    const float* b2     = (const float*)d_in[6];
    const float* w_mean = (const float*)d_in[7];
    const float* b_mean = (const float*)d_in[8];
    const float* w_var  = (const float*)d_in[9];
    const float* b_var  = (const float*)d_in[10];
    const float* W_out  = (const float*)d_in[11];

    float* out      = (float*)d_out;
    float* attn_out = out;
    float* av_out   = out + (long)Tn * Bn * Dn;
    float* mean_out = av_out + (long)Tn * Bn * Sn;
    float* var_out  = mean_out + (long)Bn * Tn * Sn;

    char* p = (char*)d_ws;
    unsigned short* inh   = (unsigned short*)p; p += 2097152;   // [2048][512]
    unsigned short* memh  = (unsigned short*)p; p += 2097152;   // contiguous after inh!
    unsigned short* inl   = (unsigned short*)p; p += 2097152;
    unsigned short* meml  = (unsigned short*)p; p += 2097152;
    unsigned short* winh  = (unsigned short*)p; p += 524288;
    unsigned short* winl  = (unsigned short*)p; p += 524288;
    unsigned short* w1b   = (unsigned short*)p; p += 204800;
    unsigned short* woutb = (unsigned short*)p; p += 1048576;
    unsigned short* w2b   = (unsigned short*)p; p += 28672;
    unsigned short* memTb = (unsigned short*)p; p += 2097152;
    unsigned short* hth   = (unsigned short*)p; p += 2097152;
    unsigned short* htl   = (unsigned short*)p; p += 2097152;
    float* ptps           = (float*)p;          p += 2097152;   // [4096][128]
    float* algn           = (float*)p;          p += 4194304;   // 4 partials
    unsigned short* concatb = (unsigned short*)p; p += 4194304;

    const long kstride = (long)Bn * Tn * Sn;

    // 0) conversions + mem transpose
    conv_trans<<<dim3(2930 + 256), 256, 0, stream>>>(
        input, mem, W_in, W1, W_out, W2,
        inh, inl, memh, meml, winh, winl, w1b, woutb, w2b, concatb, memTb);

    // 1) ht (split, hi/lo out) + pt/ps (padded ptps)   384 blocks
    gemm_ht_ptps<<<dim3(384), 256, 0, stream>>>(
        inh, inl, winh, winl, hth, htl, w1b, ptps, b1);

    // 2) align = ht @ mem^T, split, K-split x4   256 blocks
    mfma_gemm3<1, 0, 4, 0><<<dim3(2, 2, 64), 256, 0, stream>>>(
        hth, htl, memh, meml, algn, nullptr, nullptr, nullptr,
        Sn, Dn, Dn, Dn, Sn, (long)Tn * Dn, (long)Sn * Dn,
        (long)Tn * Sn, kstride);

    // 3) fused MLP (standalone, register h1)   1024 blocks
    mlp_mfma5<<<dim3(32, 32), 256, 0, stream>>>(
        ptps, w2b, b2, w_mean, b_mean, w_var, b_var, mean_out, var_out);

    // 4) fused softmax + c-GEMM (also writes av_out)   256 blocks
    softmax_c<<<dim3(8, 2, 16), 256, 0, stream>>>(
        algn, kstride, memTb, av_out, concatb);

    // 5) attn_h = tanh(concat @ W_out^T) -> (T,B,D)   256 blocks
    mfma_gemm3<0, 2, 0, 0><<<dim3(8, 32), 256, 0, stream>>>(
        concatb, nullptr, woutb, nullptr, attn_out, nullptr, nullptr, nullptr,
        Dn, 2 * Dn, 2 * Dn, 2 * Dn, Dn, 0L, 0L, 0L, 0L);
}

// Round 9
// 191.430 us; speedup vs baseline: 1.5417x; 1.5417x over previous
//
#include <hip/hip_runtime.h>
#include <hip/hip_bf16.h>
#include <math.h>

#define Bn 16
#define Tn 128
#define Sn 128
#define Dn 512
#define Hn 100
#define TT 4

typedef short short8 __attribute__((ext_vector_type(8)));
typedef float f32x4 __attribute__((ext_vector_type(4)));
typedef unsigned short ushort4v __attribute__((ext_vector_type(4)));

__device__ __forceinline__ float softplus_f(float x) {
    return fmaxf(x, 0.0f) + __logf(1.0f + __expf(-fabsf(x)));
}
__device__ __forceinline__ unsigned short f2bf(float f) {
    unsigned u = __float_as_uint(f);
    unsigned r = u + 0x7FFFu + ((u >> 16) & 1u);
    return (unsigned short)(r >> 16);
}
__device__ __forceinline__ float bf2f(unsigned short h) {
    return __uint_as_float(((unsigned)h) << 16);
}
__device__ __forceinline__ unsigned pkrn(float a, float b) {
    __hip_bfloat162 h = __float22bfloat162_rn(float2{a, b});
    return *reinterpret_cast<unsigned*>(&h);
}
struct BfPair { unsigned short h, l; };
__device__ __forceinline__ BfPair split2(float x) {
    BfPair p;
    p.h = f2bf(x);
    p.l = f2bf(x - bf2f(p.h));
    return p;
}

// ---------------------------------------------------------------------------
// Fused conversion + mem transpose (blocks >= 2930 do the transpose).
// ---------------------------------------------------------------------------
__global__ __launch_bounds__(256)
void conv_trans(const float* __restrict__ input, const float* __restrict__ mem,
                const float* __restrict__ W_in, const float* __restrict__ W1,
                const float* __restrict__ W_out, const float* __restrict__ W2,
                unsigned short* __restrict__ inh, unsigned short* __restrict__ inl,
                unsigned short* __restrict__ memh, unsigned short* __restrict__ meml,
                unsigned short* __restrict__ winh, unsigned short* __restrict__ winl,
                unsigned short* __restrict__ w1b, unsigned short* __restrict__ woutb,
                unsigned short* __restrict__ w2b, unsigned short* __restrict__ concatb,
                unsigned short* __restrict__ memTb)
{
    __shared__ float tile[64][65];
    const int bx = blockIdx.x;
    if (bx >= 2930) {
        const int b2x = bx - 2930;
        const int d0 = (b2x & 7) * 64, s0 = ((b2x >> 3) & 1) * 64, b = b2x >> 4;
        const int tid = threadIdx.x;
        const int r = tid >> 2, cb = (tid & 3) * 16;
        const float* src = mem + ((long)b * Sn + s0 + r) * Dn + d0 + cb;
        #pragma unroll
        for (int j = 0; j < 4; ++j) {
            float4 v = *(const float4*)&src[j * 4];
            tile[r][cb + j * 4 + 0] = v.x;
            tile[r][cb + j * 4 + 1] = v.y;
            tile[r][cb + j * 4 + 2] = v.z;
            tile[r][cb + j * 4 + 3] = v.w;
        }
        __syncthreads();
        unsigned short* dst = memTb + ((long)b * Dn + d0 + r) * Sn + s0 + cb;
        #pragma unroll
        for (int j = 0; j < 4; ++j) {
            ushort4v q;
            q.x = f2bf(tile[cb + j * 4 + 0][r]);
            q.y = f2bf(tile[cb + j * 4 + 1][r]);
            q.z = f2bf(tile[cb + j * 4 + 2][r]);
            q.w = f2bf(tile[cb + j * 4 + 3][r]);
            *(ushort4v*)&dst[j * 4] = q;
        }
        return;
    }
    long gid = (long)bx * 1024 + (long)threadIdx.x * 4;
    if (gid < 1048576) {
        float4 v = *(const float4*)&input[gid];
        BfPair a = split2(v.x), b = split2(v.y), c = split2(v.z), d = split2(v.w);
        ushort4v h = {a.h, b.h, c.h, d.h};
        ushort4v l = {a.l, b.l, c.l, d.l};
        *(ushort4v*)&inh[gid] = h;
        *(ushort4v*)&inl[gid] = l;
        long row = gid >> 9; int col = (int)(gid & 511);
        *(ushort4v*)&concatb[row * 1024 + 512 + col] = h;
    } else if (gid < 2097152) {
        long e = gid - 1048576;
        float4 v = *(const float4*)&mem[e];
        BfPair a = split2(v.x), b = split2(v.y), c = split2(v.z), d = split2(v.w);
        ushort4v h = {a.h, b.h, c.h, d.h};
        ushort4v l = {a.l, b.l, c.l, d.l};
        *(ushort4v*)&memh[e] = h;
        *(ushort4v*)&meml[e] = l;
    } else if (gid < 2359296) {
        long e = gid - 2097152;
        float4 v = *(const float4*)&W_in[e];
        BfPair a = split2(v.x), b = split2(v.y), c = split2(v.z), d = split2(v.w);
        ushort4v h = {a.h, b.h, c.h, d.h};
        ushort4v l = {a.l, b.l, c.l, d.l};
        *(ushort4v*)&winh[e] = h;
        *(ushort4v*)&winl[e] = l;
    } else if (gid < 2461696) {
        long e = gid - 2359296;
        float4 v = *(const float4*)&W1[e];
        ushort4v h = {f2bf(v.x), f2bf(v.y), f2bf(v.z), f2bf(v.w)};
        *(ushort4v*)&w1b[e] = h;
    } else if (gid < 2985984) {
        long e = gid - 2461696;
        float4 v = *(const float4*)&W_out[e];
        ushort4v h = {f2bf(v.x), f2bf(v.y), f2bf(v.z), f2bf(v.w)};
        *(ushort4v*)&woutb[e] = h;
    } else {
        long e = gid - 2985984;           // [112][128] padded W2
        int n = (int)(e >> 7), k = (int)(e & 127);
        ushort4v h;
        #pragma unroll
        for (int j = 0; j < 4; ++j) {
            int kj = k + j;
            float val = (n < Hn && kj < Hn) ? W2[n * Hn + kj] : 0.0f;
            h[j] = f2bf(val);
        }
        *(ushort4v*)&w2b[n * 128 + k] = h;
    }
}

// ---------------------------------------------------------------------------
// 64x64-tile bf16 MFMA GEMM body (NT). BK=64, 256 thr = 4 waves (2x2).
// ---------------------------------------------------------------------------
template<int SPLIT, int EPI, int KSPLIT, int BSEL>
__device__ __forceinline__
void gemm_body(int bx, int by, int bz_in, int upperThresh,
               const unsigned short* __restrict__ Ah, const unsigned short* __restrict__ Al,
               const unsigned short* __restrict__ Bh, const unsigned short* __restrict__ Bl,
               float* __restrict__ C, unsigned short* __restrict__ Cb,
               unsigned short* __restrict__ Cb2, const float* __restrict__ bias,
               int N, int K, int lda, int ldb, int ldc,
               long sA, long sB, long sC, long sKC,
               unsigned short* As_, unsigned short* Bs_)
{
    unsigned short* Asl = As_ + 4096;
    unsigned short* Bsl = Bs_ + 4096;

    const int tid = threadIdx.x;
    const int n0 = bx * 64;
    const long m0 = (long)by * 64;
    int bz = bz_in, kh = 0;
    if (KSPLIT) { bz = bz_in & 15; kh = bz_in >> 4; }
    Ah += (long)bz * sA;
    Bh += (long)bz * sB;
    if (SPLIT) { Al += (long)bz * sA; Bl += (long)bz * sB; }
    const bool upperB = BSEL && (by >= upperThresh);
    if (upperB) Bh += BSEL;

    const int kbeg = KSPLIT ? kh * (K / KSPLIT) : 0;
    const int kend = KSPLIT ? kbeg + (K / KSPLIT) : K;

    const int wid = tid >> 6, lane = tid & 63;
    const int lm = lane & 15, lq = lane >> 4;
    const int wm = wid & 1, wn = wid >> 1;

    const int sr = tid >> 2;
    const int sc = (tid & 3) * 2;
    const bool bok = (n0 + sr) < N;

    f32x4 acc[2][2];
    #pragma unroll
    for (int i = 0; i < 2; ++i)
        #pragma unroll
        for (int j = 0; j < 2; ++j)
            acc[i][j] = (f32x4){0.f, 0.f, 0.f, 0.f};

    for (int k0 = kbeg; k0 < kend; k0 += 64) {
        __syncthreads();
        #pragma unroll
        for (int i = 0; i < 2; ++i) {
            int c = sc + i, p = c ^ (sr & 7);
            *(short8*)&As_[sr * 64 + p * 8] =
                *(const short8*)&Ah[(m0 + sr) * lda + k0 + c * 8];
            if (SPLIT)
                *(short8*)&Asl[sr * 64 + p * 8] =
                    *(const short8*)&Al[(m0 + sr) * lda + k0 + c * 8];
        }
        #pragma unroll
        for (int i = 0; i < 2; ++i) {
            int c = sc + i, p = c ^ (sr & 7);
            short8 v = {0, 0, 0, 0, 0, 0, 0, 0};
            short8 vl = {0, 0, 0, 0, 0, 0, 0, 0};
            if (bok) {
                v = *(const short8*)&Bh[(long)(n0 + sr) * ldb + k0 + c * 8];
                if (SPLIT) vl = *(const short8*)&Bl[(long)(n0 + sr) * ldb + k0 + c * 8];
            }
            *(short8*)&Bs_[sr * 64 + p * 8] = v;
            if (SPLIT) *(short8*)&Bsl[sr * 64 + p * 8] = vl;
        }
        __syncthreads();
        #pragma unroll
        for (int kst = 0; kst < 2; ++kst) {
            short8 a[2], b[2], a2[2], b2r[2];
            const int pp = (kst * 4 + lq) ^ (lm & 7);
            #pragma unroll
            for (int mt = 0; mt < 2; ++mt) {
                int row = wm * 32 + mt * 16 + lm;
                a[mt] = *(const short8*)&As_[row * 64 + pp * 8];
                if (SPLIT) a2[mt] = *(const short8*)&Asl[row * 64 + pp * 8];
            }
            #pragma unroll
            for (int nt = 0; nt < 2; ++nt) {
                int row = wn * 32 + nt * 16 + lm;
                b[nt] = *(const short8*)&Bs_[row * 64 + pp * 8];
                if (SPLIT) b2r[nt] = *(const short8*)&Bsl[row * 64 + pp * 8];
            }
            #pragma unroll
            for (int mt = 0; mt < 2; ++mt)
                #pragma unroll
                for (int nt = 0; nt < 2; ++nt) {
                    if (SPLIT) {
                        acc[mt][nt] = __builtin_amdgcn_mfma_f32_16x16x32_bf16(
                            a2[mt], b[nt], acc[mt][nt], 0, 0, 0);
                        acc[mt][nt] = __builtin_amdgcn_mfma_f32_16x16x32_bf16(
                            a[mt], b2r[nt], acc[mt][nt], 0, 0, 0);
                    }
                    acc[mt][nt] = __builtin_amdgcn_mfma_f32_16x16x32_bf16(
                        a[mt], b[nt], acc[mt][nt], 0, 0, 0);
                }
        }
    }

    #pragma unroll
    for (int mt = 0; mt < 2; ++mt)
        #pragma unroll
        for (int nt = 0; nt < 2; ++nt)
            #pragma unroll
            for (int r = 0; r < 4; ++r) {
                long m = m0 + wm * 32 + mt * 16 + lq * 4 + r;
                int n = n0 + wn * 32 + nt * 16 + lm;
                float v = acc[mt][nt][r];
                if (EPI == 0) {
                    if (n < N)
                        C[(long)bz * sC + (long)kh * sKC + m * ldc + n] = v;
                } else if (EPI == 1) {
                    unsigned short h = f2bf(v);
                    Cb[m * ldc + n] = h;
                    Cb2[m * ldc + n] = f2bf(v - bf2f(h));
                } else if (EPI == 2) {
                    long bb = m >> 7, tt = m & 127;
                    C[tt * (Bn * Dn) + bb * Dn + n] = tanhf(v);
                } else if (EPI == 3) {
                    Cb[(long)bz * sC + m * ldc + n] = f2bf(v);
                } else {
                    float bb = (!upperB && n < Hn) ? bias[n] : 0.f;
                    C[m * ldc + n] = v + bb;
                }
            }
}

template<int SPLIT, int EPI, int KSPLIT, int BSEL>
__global__ __launch_bounds__(256)
void mfma_gemm3(const unsigned short* __restrict__ Ah, const unsigned short* __restrict__ Al,
                const unsigned short* __restrict__ Bh, const unsigned short* __restrict__ Bl,
                float* __restrict__ C, unsigned short* __restrict__ Cb,
                unsigned short* __restrict__ Cb2, const float* __restrict__ bias,
                int N, int K, int lda, int ldb, int ldc,
                long sA, long sB, long sC, long sKC)
{
    __shared__ __align__(16) unsigned short As_[(SPLIT ? 2 : 1) * 4096];
    __shared__ __align__(16) unsigned short Bs_[(SPLIT ? 2 : 1) * 4096];
    gemm_body<SPLIT, EPI, KSPLIT, BSEL>(blockIdx.x, blockIdx.y, blockIdx.z,
        (int)(gridDim.y >> 1), Ah, Al, Bh, Bl, C, Cb, Cb2, bias,
        N, K, lda, ldb, ldc, sA, sB, sC, sKC, As_, Bs_);
}

// ---------------------------------------------------------------------------
// Merged independent GEMMs: blocks 0..255 = ht (split), 256..383 = pt+ps.
// ---------------------------------------------------------------------------
__global__ __launch_bounds__(256)
void gemm_ht_ptps(const unsigned short* __restrict__ inh, const unsigned short* __restrict__ inl,
                  const unsigned short* __restrict__ winh, const unsigned short* __restrict__ winl,
                  unsigned short* __restrict__ hth, unsigned short* __restrict__ htl,
                  const unsigned short* __restrict__ w1b, float* __restrict__ ptps,
                  const float* __restrict__ b1)
{
    __shared__ __align__(16) unsigned short As_[8192];
    __shared__ __align__(16) unsigned short Bs_[8192];
    const int id = blockIdx.x;
    if (id < 256) {
        gemm_body<1, 1, 0, 0>(id & 7, id >> 3, 0, 0,
            inh, inl, winh, winl, nullptr, hth, htl, nullptr,
            Dn, Dn, Dn, Dn, Dn, 0L, 0L, 0L, 0L, As_, Bs_);
    } else {
        const int j = id - 256;
        gemm_body<0, 4, 0, 512>(j & 1, j >> 1, 0, 32,
            inh, nullptr, w1b, nullptr, ptps, nullptr, nullptr, b1,
            Hn, Dn, Dn, 2 * Dn, 128, 0L, 0L, 0L, 0L, As_, Bs_);
    }
}

// ---------------------------------------------------------------------------
// Standalone fused MLP (register-built h1 as MFMA B-operand).
// Grid (32, 32): bx = t-group of 4, by = b + 16*s_half. 256 thr = 4 waves.
// NO min-wave launch bound (R8's (256,4) forced 64 VGPRs -> 480 MB scratch
// spill traffic). hf built per-ks to keep live range minimal.
// ---------------------------------------------------------------------------
__global__ __launch_bounds__(256)
void mlp_mfma5(const float* __restrict__ ptps,
               const unsigned short* __restrict__ w2b,
               const float* __restrict__ b2,
               const float* __restrict__ w_mean, const float* __restrict__ b_mean,
               const float* __restrict__ w_var, const float* __restrict__ b_var,
               float* __restrict__ mean_out, float* __restrict__ var_out)
{
    __shared__ __align__(16) unsigned short w2s[112 * 128];   // 28672 B
    __shared__ float ptl[TT][132];
    __shared__ float wpk[224];
    __shared__ float b2l[112];

    const int tg = blockIdx.x;
    const int b  = blockIdx.y & 15;
    const int s0 = (blockIdx.y >> 4) * 64;
    const int tid = threadIdx.x;

    // stage w2 (swizzled)
    #pragma unroll
    for (int i0 = 0; i0 < 7; ++i0) {
        int i = tid + i0 * 256;
        int r_ = i >> 4, c_ = i & 15;
        *(short8*)&w2s[r_ * 128 + (c_ ^ (r_ & 7)) * 8] = *(const short8*)&w2b[i * 8];
    }
    // stage pt rows (4 x 128)
    #pragma unroll
    for (int j = 0; j < 2; ++j) {
        int i = tid + j * 256;
        int tt = i >> 7, c = i & 127;
        ptl[tt][c] = ptps[((long)b * Tn + tg * TT + tt) * 128 + c];
    }
    // stage padded wm/wv (interleaved) and b2
    if (tid < 224) {
        int g = tid >> 1;
        wpk[tid] = (g < Hn) ? ((tid & 1) ? w_var[g] : w_mean[g]) : 0.f;
    }
    if (tid < 112) b2l[tid] = (tid < Hn) ? b2[tid] : 0.f;

    const int wid = tid >> 6, lane = tid & 63;
    const int lm = lane & 15, lq = lane >> 4;
    const int s = s0 + wid * 16 + lm;

    // ps slice -> registers (lane's B-fragment source), once per block
    float psreg[4][8];
    {
        const float* psrow = ptps + (long)(2048 + b * Sn + s) * 128;
        #pragma unroll
        for (int ks = 0; ks < 4; ++ks) {
            *(float4*)&psreg[ks][0] = *(const float4*)&psrow[ks * 32 + lq * 8];
            *(float4*)&psreg[ks][4] = *(const float4*)&psrow[ks * 32 + lq * 8 + 4];
        }
    }
    const float bm = b_mean[0], bv = b_var[0];
    __syncthreads();

    for (int t = 0; t < TT; ++t) {
        f32x4 acc[7];
        #pragma unroll
        for (int j = 0; j < 7; ++j) acc[j] = (f32x4){0.f, 0.f, 0.f, 0.f};

        // per-ks: build h1 fragment in registers, then issue its 7 MFMAs
        #pragma unroll
        for (int ks = 0; ks < 4; ++ks) {
            float4 pa = *(const float4*)&ptl[t][ks * 32 + lq * 8];
            float4 pb = *(const float4*)&ptl[t][ks * 32 + lq * 8 + 4];
            float x0 = softplus_f(psreg[ks][0] + pa.x);
            float x1 = softplus_f(psreg[ks][1] + pa.y);
            float x2 = softplus_f(psreg[ks][2] + pa.z);
            float x3 = softplus_f(psreg[ks][3] + pa.w);
            float x4 = softplus_f(psreg[ks][4] + pb.x);
            float x5 = softplus_f(psreg[ks][5] + pb.y);
            float x6 = softplus_f(psreg[ks][6] + pb.z);
            float x7 = softplus_f(psreg[ks][7] + pb.w);
            union { uint4 u4; short8 s8; } cv;
            cv.u4.x = pkrn(x0, x1); cv.u4.y = pkrn(x2, x3);
            cv.u4.z = pkrn(x4, x5); cv.u4.w = pkrn(x6, x7);
            const short8 hf = cv.s8;
            const int p = (ks * 4 + lq) ^ (lm & 7);
            #pragma unroll
            for (int mt = 0; mt < 7; ++mt) {
                short8 w = *(const short8*)&w2s[(mt * 16 + lm) * 128 + p * 8];
                acc[mt] = __builtin_amdgcn_mfma_f32_16x16x32_bf16(w, hf, acc[mt], 0, 0, 0);
            }
        }
        // epilogue: in-lane reduce over 28 g's, butterfly over quads
        float sM = 0.f, sV = 0.f;
        #pragma unroll
        for (int mt = 0; mt < 7; ++mt) {
            const int g0 = mt * 16 + lq * 4;
            float4 bg = *(const float4*)&b2l[g0];
            float4 wa = *(const float4*)&wpk[g0 * 2];
            float4 wb = *(const float4*)&wpk[g0 * 2 + 4];
            float h2;
            h2 = softplus_f(acc[mt][0] + bg.x); sM = fmaf(h2, wa.x, sM); sV = fmaf(h2, wa.y, sV);
            h2 = softplus_f(acc[mt][1] + bg.y); sM = fmaf(h2, wa.z, sM); sV = fmaf(h2, wa.w, sV);
            h2 = softplus_f(acc[mt][2] + bg.z); sM = fmaf(h2, wb.x, sM); sV = fmaf(h2, wb.y, sV);
            h2 = softplus_f(acc[mt][3] + bg.w); sM = fmaf(h2, wb.z, sM); sV = fmaf(h2, wb.w, sV);
        }
        sM += __shfl_xor(sM, 16); sM += __shfl_xor(sM, 32);
        sV += __shfl_xor(sV, 16); sV += __shfl_xor(sV, 32);
        if (lq == 0) {
            const long base = ((long)b * Tn + tg * TT + t) * Sn + s;
            mean_out[base] = softplus_f(sM + bm);
            var_out[base]  = softplus_f(sV + bv);
        }
    }
}

// ---------------------------------------------------------------------------
// Fused softmax + c-GEMM. Grid (8 nt, 2 mt, 16 b), 256 threads.
// ---------------------------------------------------------------------------
__global__ __launch_bounds__(256)
void softmax_c(const float* __restrict__ algn, long kstride,
               const unsigned short* __restrict__ memTb,
               float* __restrict__ av_out, unsigned short* __restrict__ concatb)
{
    __shared__ __align__(16) unsigned short avs[64 * 128];
    __shared__ __align__(16) unsigned short Bs[64 * 128];

    const int ntb = blockIdx.x, mtb = blockIdx.y, b = blockIdx.z;
    const int tid = threadIdx.x;
    const int r = tid >> 2, q = tid & 3;

    // phase 1: softmax rows (4 threads per row, 32 cols each)
    float v[32];
    {
        const float* arow = algn + ((long)b * Tn + mtb * 64 + r) * Sn + q * 32;
        #pragma unroll
        for (int j = 0; j < 8; ++j) {
            float4 a0 = *(const float4*)&arow[j * 4];
            float4 a1 = *(const float4*)&arow[j * 4 + kstride];
            float4 a2 = *(const float4*)&arow[j * 4 + 2 * kstride];
            float4 a3 = *(const float4*)&arow[j * 4 + 3 * kstride];
            v[j * 4 + 0] = a0.x + a1.x + a2.x + a3.x;
            v[j * 4 + 1] = a0.y + a1.y + a2.y + a3.y;
            v[j * 4 + 2] = a0.z + a1.z + a2.z + a3.z;
            v[j * 4 + 3] = a0.w + a1.w + a2.w + a3.w;
        }
    }
    float mx = v[0];
    #pragma unroll
    for (int i = 1; i < 32; ++i) mx = fmaxf(mx, v[i]);
    mx = fmaxf(mx, __shfl_xor(mx, 1));
    mx = fmaxf(mx, __shfl_xor(mx, 2));
    float sum = 0.f;
    #pragma unroll
    for (int i = 0; i < 32; ++i) { v[i] = __expf(v[i] - mx); sum += v[i]; }
    sum += __shfl_xor(sum, 1);
    sum += __shfl_xor(sum, 2);
    const float inv = 1.0f / sum;

    if (ntb == 0) {
        float* dst = av_out + (long)(mtb * 64 + r) * (Bn * Sn) + b * Sn + q * 32;
        #pragma unroll
        for (int j = 0; j < 8; ++j) {
            float4 o = {v[j*4]*inv, v[j*4+1]*inv, v[j*4+2]*inv, v[j*4+3]*inv};
            *(float4*)&dst[j * 4] = o;
        }
    }
    #pragma unroll
    for (int i = 0; i < 4; ++i) {
        int c = q * 4 + i;
        uint4 u;
        u.x = pkrn(v[i*8+0]*inv, v[i*8+1]*inv);
        u.y = pkrn(v[i*8+2]*inv, v[i*8+3]*inv);
        u.z = pkrn(v[i*8+4]*inv, v[i*8+5]*inv);
        u.w = pkrn(v[i*8+6]*inv, v[i*8+7]*inv);
        *(uint4*)&avs[r * 128 + (c ^ (r & 7)) * 8] = u;
    }
    // stage B (memT rows = d)
    #pragma unroll
    for (int j = 0; j < 4; ++j) {
        int idx = tid * 4 + j;
        int rB = idx >> 4, cB = idx & 15;
        *(short8*)&Bs[rB * 128 + (cB ^ (rB & 7)) * 8] =
            *(const short8*)&memTb[((long)b * Dn + ntb * 64 + rB) * Sn + cB * 8];
    }
    __syncthreads();

    // phase 2: c tile = avs @ Bs^T (K=128)
    const int wid = tid >> 6, lane = tid & 63;
    const int lm = lane & 15, lq = lane >> 4;
    const int wm = wid & 1, wn = wid >> 1;

    f32x4 acc[2][2];
    #pragma unroll
    for (int i = 0; i < 2; ++i)
        #pragma unroll
        for (int j = 0; j < 2; ++j) acc[i][j] = (f32x4){0.f, 0.f, 0.f, 0.f};

    #pragma unroll
    for (int kk = 0; kk < 4; ++kk) {
        const int p = (kk * 4 + lq) ^ (lm & 7);
        short8 a0 = *(const short8*)&avs[(wm * 32 + lm) * 128 + p * 8];
        short8 a1 = *(const short8*)&avs[(wm * 32 + 16 + lm) * 128 + p * 8];
        short8 b0 = *(const short8*)&Bs[(wn * 32 + lm) * 128 + p * 8];
        short8 b1 = *(const short8*)&Bs[(wn * 32 + 16 + lm) * 128 + p * 8];
        acc[0][0] = __builtin_amdgcn_mfma_f32_16x16x32_bf16(a0, b0, acc[0][0], 0, 0, 0);
        acc[0][1] = __builtin_amdgcn_mfma_f32_16x16x32_bf16(a0, b1, acc[0][1], 0, 0, 0);
        acc[1][0] = __builtin_amdgcn_mfma_f32_16x16x32_bf16(a1, b0, acc[1][0], 0, 0, 0);
        acc[1][1] = __builtin_amdgcn_mfma_f32_16x16x32_bf16(a1, b1, acc[1][1], 0, 0, 0);
    }
    #pragma unroll
    for (int mt = 0; mt < 2; ++mt)
        #pragma unroll
        for (int nt = 0; nt < 2; ++nt)
            #pragma unroll
            for (int rr = 0; rr < 4; ++rr) {
                long mrow = (long)b * Tn + mtb * 64 + wm * 32 + mt * 16 + lq * 4 + rr;
                int n = ntb * 64 + wn * 32 + nt * 16 + lm;
                concatb[mrow * 1024 + n] = f2bf(acc[mt][nt][rr]);
            }
}

// ---------------------------------------------------------------------------
extern "C" void kernel_launch(void* const* d_in, const int* in_sizes, int n_in,
                              void* d_out, int out_size, void* d_ws, size_t ws_size,
                              hipStream_t stream)
{
    (void)in_sizes; (void)n_in; (void)out_size; (void)ws_size;

    const float* input  = (const float*)d_in[0];
    const float* mem    = (const float*)d_in[1];
    const float* W_in   = (const float*)d_in[2];
    const float* W1     = (const float*)d_in[3];
    const float* b1     = (const float*)d_in[4];
    const float* W2     = (const float*)d_in[5];
    const float* b2     = (const float*)d_in[6];
    const float* w_mean = (const float*)d_in[7];
    const float* b_mean = (const float*)d_in[8];
    const float* w_var  = (const float*)d_in[9];
    const float* b_var  = (const float*)d_in[10];
    const float* W_out  = (const float*)d_in[11];

    float* out      = (float*)d_out;
    float* attn_out = out;
    float* av_out   = out + (long)Tn * Bn * Dn;
    float* mean_out = av_out + (long)Tn * Bn * Sn;
    float* var_out  = mean_out + (long)Bn * Tn * Sn;

    char* p = (char*)d_ws;
    unsigned short* inh   = (unsigned short*)p; p += 2097152;   // [2048][512]
    unsigned short* memh  = (unsigned short*)p; p += 2097152;   // contiguous after inh!
    unsigned short* inl   = (unsigned short*)p; p += 2097152;
    unsigned short* meml  = (unsigned short*)p; p += 2097152;
    unsigned short* winh  = (unsigned short*)p; p += 524288;
    unsigned short* winl  = (unsigned short*)p; p += 524288;
    unsigned short* w1b   = (unsigned short*)p; p += 204800;
    unsigned short* woutb = (unsigned short*)p; p += 1048576;
    unsigned short* w2b   = (unsigned short*)p; p += 28672;
    unsigned short* memTb = (unsigned short*)p; p += 2097152;
    unsigned short* hth   = (unsigned short*)p; p += 2097152;
    unsigned short* htl   = (unsigned short*)p; p += 2097152;
    float* ptps           = (float*)p;          p += 2097152;   // [4096][128]
    float* algn           = (float*)p;          p += 4194304;   // 4 partials
    unsigned short* concatb = (unsigned short*)p; p += 4194304;

    const long kstride = (long)Bn * Tn * Sn;

    // 0) conversions + mem transpose
    conv_trans<<<dim3(2930 + 256), 256, 0, stream>>>(
        input, mem, W_in, W1, W_out, W2,
        inh, inl, memh, meml, winh, winl, w1b, woutb, w2b, concatb, memTb);

    // 1) ht (split, hi/lo out) + pt/ps (padded ptps)   384 blocks
    gemm_ht_ptps<<<dim3(384), 256, 0, stream>>>(
        inh, inl, winh, winl, hth, htl, w1b, ptps, b1);

    // 2) align = ht @ mem^T, split, K-split x4   256 blocks
    mfma_gemm3<1, 0, 4, 0><<<dim3(2, 2, 64), 256, 0, stream>>>(
        hth, htl, memh, meml, algn, nullptr, nullptr, nullptr,
        Sn, Dn, Dn, Dn, Sn, (long)Tn * Dn, (long)Sn * Dn,
        (long)Tn * Sn, kstride);

    // 3) fused MLP (standalone, register h1)   1024 blocks
    mlp_mfma5<<<dim3(32, 32), 256, 0, stream>>>(
        ptps, w2b, b2, w_mean, b_mean, w_var, b_var, mean_out, var_out);

    // 4) fused softmax + c-GEMM (also writes av_out)   256 blocks
    softmax_c<<<dim3(8, 2, 16), 256, 0, stream>>>(
        algn, kstride, memTb, av_out, concatb);

    // 5) attn_h = tanh(concat @ W_out^T) -> (T,B,D)   256 blocks
    mfma_gemm3<0, 2, 0, 0><<<dim3(8, 32), 256, 0, stream>>>(
        concatb, nullptr, woutb, nullptr, attn_out, nullptr, nullptr, nullptr,
        Dn, 2 * Dn, 2 * Dn, 2 * Dn, Dn, 0L, 0L, 0L, 0L);
}

// Round 10
// 172.498 us; speedup vs baseline: 1.7109x; 1.1097x over previous
//
#include <hip/hip_runtime.h>
#include <hip/hip_bf16.h>
#include <math.h>

#define Bn 16
#define Tn 128
#define Sn 128
#define Dn 512
#define Hn 100
#define TT2 2

typedef short short8 __attribute__((ext_vector_type(8)));
typedef float f32x4 __attribute__((ext_vector_type(4)));
typedef unsigned short ushort4v __attribute__((ext_vector_type(4)));

__device__ __forceinline__ float softplus_f(float x) {
    return fmaxf(x, 0.0f) + __logf(1.0f + __expf(-fabsf(x)));
}
__device__ __forceinline__ unsigned short f2bf(float f) {
    unsigned u = __float_as_uint(f);
    unsigned r = u + 0x7FFFu + ((u >> 16) & 1u);
    return (unsigned short)(r >> 16);
}
__device__ __forceinline__ float bf2f(unsigned short h) {
    return __uint_as_float(((unsigned)h) << 16);
}
__device__ __forceinline__ unsigned pkrn(float a, float b) {
    __hip_bfloat162 h = __float22bfloat162_rn(float2{a, b});
    return *reinterpret_cast<unsigned*>(&h);
}
struct BfPair { unsigned short h, l; };
__device__ __forceinline__ BfPair split2(float x) {
    BfPair p;
    p.h = f2bf(x);
    p.l = f2bf(x - bf2f(p.h));
    return p;
}

// ---------------------------------------------------------------------------
// Fused conversion + mem transpose (blocks >= 2930 do the transpose).
// ---------------------------------------------------------------------------
__global__ __launch_bounds__(256)
void conv_trans(const float* __restrict__ input, const float* __restrict__ mem,
                const float* __restrict__ W_in, const float* __restrict__ W1,
                const float* __restrict__ W_out, const float* __restrict__ W2,
                unsigned short* __restrict__ inh, unsigned short* __restrict__ inl,
                unsigned short* __restrict__ memh, unsigned short* __restrict__ meml,
                unsigned short* __restrict__ winh, unsigned short* __restrict__ winl,
                unsigned short* __restrict__ w1b, unsigned short* __restrict__ woutb,
                unsigned short* __restrict__ w2b, unsigned short* __restrict__ concatb,
                unsigned short* __restrict__ memTb)
{
    __shared__ float tile[64][65];
    const int bx = blockIdx.x;
    if (bx >= 2930) {
        const int b2x = bx - 2930;
        const int d0 = (b2x & 7) * 64, s0 = ((b2x >> 3) & 1) * 64, b = b2x >> 4;
        const int tid = threadIdx.x;
        const int r = tid >> 2, cb = (tid & 3) * 16;
        const float* src = mem + ((long)b * Sn + s0 + r) * Dn + d0 + cb;
        #pragma unroll
        for (int j = 0; j < 4; ++j) {
            float4 v = *(const float4*)&src[j * 4];
            tile[r][cb + j * 4 + 0] = v.x;
            tile[r][cb + j * 4 + 1] = v.y;
            tile[r][cb + j * 4 + 2] = v.z;
            tile[r][cb + j * 4 + 3] = v.w;
        }
        __syncthreads();
        unsigned short* dst = memTb + ((long)b * Dn + d0 + r) * Sn + s0 + cb;
        #pragma unroll
        for (int j = 0; j < 4; ++j) {
            ushort4v q;
            q.x = f2bf(tile[cb + j * 4 + 0][r]);
            q.y = f2bf(tile[cb + j * 4 + 1][r]);
            q.z = f2bf(tile[cb + j * 4 + 2][r]);
            q.w = f2bf(tile[cb + j * 4 + 3][r]);
            *(ushort4v*)&dst[j * 4] = q;
        }
        return;
    }
    long gid = (long)bx * 1024 + (long)threadIdx.x * 4;
    if (gid < 1048576) {
        float4 v = *(const float4*)&input[gid];
        BfPair a = split2(v.x), b = split2(v.y), c = split2(v.z), d = split2(v.w);
        ushort4v h = {a.h, b.h, c.h, d.h};
        ushort4v l = {a.l, b.l, c.l, d.l};
        *(ushort4v*)&inh[gid] = h;
        *(ushort4v*)&inl[gid] = l;
        long row = gid >> 9; int col = (int)(gid & 511);
        *(ushort4v*)&concatb[row * 1024 + 512 + col] = h;
    } else if (gid < 2097152) {
        long e = gid - 1048576;
        float4 v = *(const float4*)&mem[e];
        BfPair a = split2(v.x), b = split2(v.y), c = split2(v.z), d = split2(v.w);
        ushort4v h = {a.h, b.h, c.h, d.h};
        ushort4v l = {a.l, b.l, c.l, d.l};
        *(ushort4v*)&memh[e] = h;
        *(ushort4v*)&meml[e] = l;
    } else if (gid < 2359296) {
        long e = gid - 2097152;
        float4 v = *(const float4*)&W_in[e];
        BfPair a = split2(v.x), b = split2(v.y), c = split2(v.z), d = split2(v.w);
        ushort4v h = {a.h, b.h, c.h, d.h};
        ushort4v l = {a.l, b.l, c.l, d.l};
        *(ushort4v*)&winh[e] = h;
        *(ushort4v*)&winl[e] = l;
    } else if (gid < 2461696) {
        long e = gid - 2359296;
        float4 v = *(const float4*)&W1[e];
        ushort4v h = {f2bf(v.x), f2bf(v.y), f2bf(v.z), f2bf(v.w)};
        *(ushort4v*)&w1b[e] = h;
    } else if (gid < 2985984) {
        long e = gid - 2461696;
        float4 v = *(const float4*)&W_out[e];
        ushort4v h = {f2bf(v.x), f2bf(v.y), f2bf(v.z), f2bf(v.w)};
        *(ushort4v*)&woutb[e] = h;
    } else {
        long e = gid - 2985984;           // [112][128] padded W2
        int n = (int)(e >> 7), k = (int)(e & 127);
        ushort4v h;
        #pragma unroll
        for (int j = 0; j < 4; ++j) {
            int kj = k + j;
            float val = (n < Hn && kj < Hn) ? W2[n * Hn + kj] : 0.0f;
            h[j] = f2bf(val);
        }
        *(ushort4v*)&w2b[n * 128 + k] = h;
    }
}

// ---------------------------------------------------------------------------
// 64x64-tile bf16 MFMA GEMM body (NT). BK=64, 256 thr = 4 waves (2x2).
// Register-prefetch double-buffered K-loop: tile k+1's global loads are in
// flight while tile k is computed (critical at 1 block/CU occupancy).
// ---------------------------------------------------------------------------
template<int SPLIT, int EPI, int KSPLIT, int BSEL>
__device__ __forceinline__
void gemm_body(int bx, int by, int bz_in, int upperThresh,
               const unsigned short* __restrict__ Ah, const unsigned short* __restrict__ Al,
               const unsigned short* __restrict__ Bh, const unsigned short* __restrict__ Bl,
               float* __restrict__ C, unsigned short* __restrict__ Cb,
               unsigned short* __restrict__ Cb2, const float* __restrict__ bias,
               int N, int K, int lda, int ldb, int ldc,
               long sA, long sB, long sC, long sKC,
               unsigned short* As_, unsigned short* Bs_)
{
    unsigned short* Asl = As_ + 4096;
    unsigned short* Bsl = Bs_ + 4096;

    const int tid = threadIdx.x;
    const int n0 = bx * 64;
    const long m0 = (long)by * 64;
    int bz = bz_in, kh = 0;
    if (KSPLIT) { bz = bz_in & 15; kh = bz_in >> 4; }
    Ah += (long)bz * sA;
    Bh += (long)bz * sB;
    if (SPLIT) { Al += (long)bz * sA; Bl += (long)bz * sB; }
    const bool upperB = BSEL && (by >= upperThresh);
    if (upperB) Bh += BSEL;

    const int kbeg = KSPLIT ? kh * (K / KSPLIT) : 0;
    const int kend = KSPLIT ? kbeg + (K / KSPLIT) : K;

    const int wid = tid >> 6, lane = tid & 63;
    const int lm = lane & 15, lq = lane >> 4;
    const int wm = wid & 1, wn = wid >> 1;

    const int sr = tid >> 2;
    const int sc = (tid & 3) * 2;
    const bool bok = (n0 + sr) < N;

    f32x4 acc[2][2];
    #pragma unroll
    for (int i = 0; i < 2; ++i)
        #pragma unroll
        for (int j = 0; j < 2; ++j)
            acc[i][j] = (f32x4){0.f, 0.f, 0.f, 0.f};

    short8 pA[2], pB[2], pAl[2], pBl[2];
    const short8 zz = {0, 0, 0, 0, 0, 0, 0, 0};

    // prologue fetch (tile kbeg)
    #pragma unroll
    for (int i = 0; i < 2; ++i) {
        int c = sc + i;
        pA[i] = *(const short8*)&Ah[(m0 + sr) * lda + kbeg + c * 8];
        if (SPLIT) pAl[i] = *(const short8*)&Al[(m0 + sr) * lda + kbeg + c * 8];
        pB[i] = bok ? *(const short8*)&Bh[(long)(n0 + sr) * ldb + kbeg + c * 8] : zz;
        if (SPLIT) pBl[i] = bok ? *(const short8*)&Bl[(long)(n0 + sr) * ldb + kbeg + c * 8] : zz;
    }

    for (int k0 = kbeg; k0 < kend; k0 += 64) {
        __syncthreads();
        // store prefetched tile to LDS
        #pragma unroll
        for (int i = 0; i < 2; ++i) {
            int c = sc + i, p = c ^ (sr & 7);
            *(short8*)&As_[sr * 64 + p * 8] = pA[i];
            *(short8*)&Bs_[sr * 64 + p * 8] = pB[i];
            if (SPLIT) {
                *(short8*)&Asl[sr * 64 + p * 8] = pAl[i];
                *(short8*)&Bsl[sr * 64 + p * 8] = pBl[i];
            }
        }
        __syncthreads();
        // issue next tile's loads (overlap with compute below)
        if (k0 + 64 < kend) {
            const int kn = k0 + 64;
            #pragma unroll
            for (int i = 0; i < 2; ++i) {
                int c = sc + i;
                pA[i] = *(const short8*)&Ah[(m0 + sr) * lda + kn + c * 8];
                if (SPLIT) pAl[i] = *(const short8*)&Al[(m0 + sr) * lda + kn + c * 8];
                pB[i] = bok ? *(const short8*)&Bh[(long)(n0 + sr) * ldb + kn + c * 8] : zz;
                if (SPLIT) pBl[i] = bok ? *(const short8*)&Bl[(long)(n0 + sr) * ldb + kn + c * 8] : zz;
            }
        }
        // compute current tile
        #pragma unroll
        for (int kst = 0; kst < 2; ++kst) {
            short8 a[2], b[2], a2[2], b2r[2];
            const int pp = (kst * 4 + lq) ^ (lm & 7);
            #pragma unroll
            for (int mt = 0; mt < 2; ++mt) {
                int row = wm * 32 + mt * 16 + lm;
                a[mt] = *(const short8*)&As_[row * 64 + pp * 8];
                if (SPLIT) a2[mt] = *(const short8*)&Asl[row * 64 + pp * 8];
            }
            #pragma unroll
            for (int nt = 0; nt < 2; ++nt) {
                int row = wn * 32 + nt * 16 + lm;
                b[nt] = *(const short8*)&Bs_[row * 64 + pp * 8];
                if (SPLIT) b2r[nt] = *(const short8*)&Bsl[row * 64 + pp * 8];
            }
            #pragma unroll
            for (int mt = 0; mt < 2; ++mt)
                #pragma unroll
                for (int nt = 0; nt < 2; ++nt) {
                    if (SPLIT) {
                        acc[mt][nt] = __builtin_amdgcn_mfma_f32_16x16x32_bf16(
                            a2[mt], b[nt], acc[mt][nt], 0, 0, 0);
                        acc[mt][nt] = __builtin_amdgcn_mfma_f32_16x16x32_bf16(
                            a[mt], b2r[nt], acc[mt][nt], 0, 0, 0);
                    }
                    acc[mt][nt] = __builtin_amdgcn_mfma_f32_16x16x32_bf16(
                        a[mt], b[nt], acc[mt][nt], 0, 0, 0);
                }
        }
    }

    #pragma unroll
    for (int mt = 0; mt < 2; ++mt)
        #pragma unroll
        for (int nt = 0; nt < 2; ++nt)
            #pragma unroll
            for (int r = 0; r < 4; ++r) {
                long m = m0 + wm * 32 + mt * 16 + lq * 4 + r;
                int n = n0 + wn * 32 + nt * 16 + lm;
                float v = acc[mt][nt][r];
                if (EPI == 0) {
                    if (n < N)
                        C[(long)bz * sC + (long)kh * sKC + m * ldc + n] = v;
                } else if (EPI == 1) {
                    unsigned short h = f2bf(v);
                    Cb[m * ldc + n] = h;
                    Cb2[m * ldc + n] = f2bf(v - bf2f(h));
                } else if (EPI == 2) {
                    long bb = m >> 7, tt = m & 127;
                    C[tt * (Bn * Dn) + bb * Dn + n] = tanhf(v);
                } else if (EPI == 3) {
                    Cb[(long)bz * sC + m * ldc + n] = f2bf(v);
                } else {
                    float bb = (!upperB && n < Hn) ? bias[n] : 0.f;
                    C[m * ldc + n] = v + bb;
                }
            }
}

template<int SPLIT, int EPI, int KSPLIT, int BSEL>
__global__ __launch_bounds__(256)
void mfma_gemm3(const unsigned short* __restrict__ Ah, const unsigned short* __restrict__ Al,
                const unsigned short* __restrict__ Bh, const unsigned short* __restrict__ Bl,
                float* __restrict__ C, unsigned short* __restrict__ Cb,
                unsigned short* __restrict__ Cb2, const float* __restrict__ bias,
                int N, int K, int lda, int ldb, int ldc,
                long sA, long sB, long sC, long sKC)
{
    __shared__ __align__(16) unsigned short As_[(SPLIT ? 2 : 1) * 4096];
    __shared__ __align__(16) unsigned short Bs_[(SPLIT ? 2 : 1) * 4096];
    gemm_body<SPLIT, EPI, KSPLIT, BSEL>(blockIdx.x, blockIdx.y, blockIdx.z,
        (int)(gridDim.y >> 1), Ah, Al, Bh, Bl, C, Cb, Cb2, bias,
        N, K, lda, ldb, ldc, sA, sB, sC, sKC, As_, Bs_);
}

// ---------------------------------------------------------------------------
// Merged independent GEMMs: blocks 0..255 = ht (split), 256..383 = pt+ps.
// ---------------------------------------------------------------------------
__global__ __launch_bounds__(256)
void gemm_ht_ptps(const unsigned short* __restrict__ inh, const unsigned short* __restrict__ inl,
                  const unsigned short* __restrict__ winh, const unsigned short* __restrict__ winl,
                  unsigned short* __restrict__ hth, unsigned short* __restrict__ htl,
                  const unsigned short* __restrict__ w1b, float* __restrict__ ptps,
                  const float* __restrict__ b1)
{
    __shared__ __align__(16) unsigned short As_[8192];
    __shared__ __align__(16) unsigned short Bs_[8192];
    const int id = blockIdx.x;
    if (id < 256) {
        gemm_body<1, 1, 0, 0>(id & 7, id >> 3, 0, 0,
            inh, inl, winh, winl, nullptr, hth, htl, nullptr,
            Dn, Dn, Dn, Dn, Dn, 0L, 0L, 0L, 0L, As_, Bs_);
    } else {
        const int j = id - 256;
        gemm_body<0, 4, 0, 512>(j & 1, j >> 1, 0, 32,
            inh, nullptr, w1b, nullptr, ptps, nullptr, nullptr, b1,
            Hn, Dn, Dn, 2 * Dn, 128, 0L, 0L, 0L, 0L, As_, Bs_);
    }
}

// ---------------------------------------------------------------------------
// Fused MLP v4 (R6's mlp_mfma4, measured 52 us). Block = (t-group of TT2=2,
// b*2 + s-half). 256 thr = 4 waves. ptps padded [4096][128] fp32.
// ---------------------------------------------------------------------------
__global__ __launch_bounds__(256)
void mlp_mfma4(const float* __restrict__ ptps,
               const unsigned short* __restrict__ w2b,
               const float* __restrict__ b2,
               const float* __restrict__ w_mean, const float* __restrict__ b_mean,
               const float* __restrict__ w_var, const float* __restrict__ b_var,
               float* __restrict__ mean_out, float* __restrict__ var_out)
{
    __shared__ __align__(16) unsigned short h1s[64 * 128];
    __shared__ __align__(16) unsigned short w2s[112 * 128];
    __shared__ float ptl[TT2][140];
    __shared__ float b2p[112], wmp[112], wvp[112];

    const int tg = blockIdx.x;
    const int b  = blockIdx.y >> 1;
    const int s0 = (blockIdx.y & 1) * 64;
    const int tid = threadIdx.x;

    // stage w2 (swizzled)
    #pragma unroll
    for (int i0 = 0; i0 < 7; ++i0) {
        int i = tid + i0 * 256;
        int r_ = i >> 4, c_ = i & 15;
        *(short8*)&w2s[r_ * 128 + (c_ ^ (r_ & 7)) * 8] = *(const short8*)&w2b[i * 8];
    }
    // stage pt rows (1 float/thread, bank-offset layout)
    {
        int t = tid >> 7, c = tid & 127;
        ptl[t][c + 4 * (c >> 5)] =
            ptps[((long)b * Tn + tg * TT2 + t) * 128 + c];
    }
    if (tid < 112) {
        b2p[tid] = (tid < Hn) ? b2[tid] : 0.f;
        wmp[tid] = (tid < Hn) ? w_mean[tid] : 0.f;
        wvp[tid] = (tid < Hn) ? w_var[tid] : 0.f;
    }

    // ps tile -> registers: row r, strided chunks c = cb + 4*i (8 cols each)
    const int r = tid >> 2, cb = tid & 3;
    float psreg[4][8];
    {
        const float* psrow = ptps + (long)(2048 + b * Sn + s0 + r) * 128;
        #pragma unroll
        for (int i = 0; i < 4; ++i) {
            int col = (cb + 4 * i) * 8;
            *(float4*)&psreg[i][0] = *(const float4*)&psrow[col];
            *(float4*)&psreg[i][4] = *(const float4*)&psrow[col + 4];
        }
    }
    __syncthreads();

    const int wid = tid >> 6, lane = tid & 63;
    const int lm = lane & 15, lq = lane >> 4;
    const float bm = b_mean[0], bv = b_var[0];

    for (int t = 0; t < TT2; ++t) {
        // h1 = softplus(ps + pt), packed to bf16, swizzled LDS store
        #pragma unroll
        for (int i = 0; i < 4; ++i) {
            const int c = cb + 4 * i;
            const int col = c * 8;
            const int base = col + 4 * (col >> 5);   // = cb*8 + 36*i
            float4 pa = *(const float4*)&ptl[t][base];
            float4 pb = *(const float4*)&ptl[t][base + 4];
            float x0 = softplus_f(psreg[i][0] + pa.x);
            float x1 = softplus_f(psreg[i][1] + pa.y);
            float x2 = softplus_f(psreg[i][2] + pa.z);
            float x3 = softplus_f(psreg[i][3] + pa.w);
            float x4 = softplus_f(psreg[i][4] + pb.x);
            float x5 = softplus_f(psreg[i][5] + pb.y);
            float x6 = softplus_f(psreg[i][6] + pb.z);
            float x7 = softplus_f(psreg[i][7] + pb.w);
            uint4 u;
            u.x = pkrn(x0, x1); u.y = pkrn(x2, x3);
            u.z = pkrn(x4, x5); u.w = pkrn(x6, x7);
            *(uint4*)&h1s[r * 128 + (c ^ (r & 7)) * 8] = u;
        }
        __syncthreads();

        // h2 = h1 @ W2^T
        f32x4 acc[7];
        #pragma unroll
        for (int j = 0; j < 7; ++j) acc[j] = (f32x4){0.f, 0.f, 0.f, 0.f};
        #pragma unroll
        for (int ks = 0; ks < 4; ++ks) {
            const int p = (ks * 4 + lq) ^ (lm & 7);
            short8 a = *(const short8*)&h1s[(wid * 16 + lm) * 128 + p * 8];
            #pragma unroll
            for (int nt = 0; nt < 7; ++nt) {
                short8 bf = *(const short8*)&w2s[(nt * 16 + lm) * 128 + p * 8];
                acc[nt] = __builtin_amdgcn_mfma_f32_16x16x32_bf16(a, bf, acc[nt], 0, 0, 0);
            }
        }

        // epilogue
        float sM[4] = {}, sV[4] = {};
        #pragma unroll
        for (int nt = 0; nt < 7; ++nt) {
            int g = nt * 16 + lm;
            float bg = b2p[g], wm_ = wmp[g], wv_ = wvp[g];
            #pragma unroll
            for (int rr = 0; rr < 4; ++rr) {
                float h2 = softplus_f(acc[nt][rr] + bg);
                sM[rr] = fmaf(h2, wm_, sM[rr]);
                sV[rr] = fmaf(h2, wv_, sV[rr]);
            }
        }
        #pragma unroll
        for (int off = 1; off < 16; off <<= 1)
            #pragma unroll
            for (int rr = 0; rr < 4; ++rr) {
                sM[rr] += __shfl_xor(sM[rr], off);
                sV[rr] += __shfl_xor(sV[rr], off);
            }
        if (lm == 0) {
            const long base = ((long)b * Tn + tg * TT2 + t) * Sn + s0;
            #pragma unroll
            for (int rr = 0; rr < 4; ++rr) {
                int row = wid * 16 + lq * 4 + rr;
                mean_out[base + row] = softplus_f(sM[rr] + bm);
                var_out[base + row]  = softplus_f(sV[rr] + bv);
            }
        }
        __syncthreads();
    }
}

// ---------------------------------------------------------------------------
// Fused softmax + c-GEMM. Grid (8 nt, 2 mt, 16 b), 256 threads.
// ---------------------------------------------------------------------------
__global__ __launch_bounds__(256)
void softmax_c(const float* __restrict__ algn, long kstride,
               const unsigned short* __restrict__ memTb,
               float* __restrict__ av_out, unsigned short* __restrict__ concatb)
{
    __shared__ __align__(16) unsigned short avs[64 * 128];
    __shared__ __align__(16) unsigned short Bs[64 * 128];

    const int ntb = blockIdx.x, mtb = blockIdx.y, b = blockIdx.z;
    const int tid = threadIdx.x;
    const int r = tid >> 2, q = tid & 3;

    // phase 1: softmax rows (4 threads per row, 32 cols each)
    float v[32];
    {
        const float* arow = algn + ((long)b * Tn + mtb * 64 + r) * Sn + q * 32;
        #pragma unroll
        for (int j = 0; j < 8; ++j) {
            float4 a0 = *(const float4*)&arow[j * 4];
            float4 a1 = *(const float4*)&arow[j * 4 + kstride];
            float4 a2 = *(const float4*)&arow[j * 4 + 2 * kstride];
            float4 a3 = *(const float4*)&arow[j * 4 + 3 * kstride];
            v[j * 4 + 0] = a0.x + a1.x + a2.x + a3.x;
            v[j * 4 + 1] = a0.y + a1.y + a2.y + a3.y;
            v[j * 4 + 2] = a0.z + a1.z + a2.z + a3.z;
            v[j * 4 + 3] = a0.w + a1.w + a2.w + a3.w;
        }
    }
    float mx = v[0];
    #pragma unroll
    for (int i = 1; i < 32; ++i) mx = fmaxf(mx, v[i]);
    mx = fmaxf(mx, __shfl_xor(mx, 1));
    mx = fmaxf(mx, __shfl_xor(mx, 2));
    float sum = 0.f;
    #pragma unroll
    for (int i = 0; i < 32; ++i) { v[i] = __expf(v[i] - mx); sum += v[i]; }
    sum += __shfl_xor(sum, 1);
    sum += __shfl_xor(sum, 2);
    const float inv = 1.0f / sum;

    if (ntb == 0) {
        float* dst = av_out + (long)(mtb * 64 + r) * (Bn * Sn) + b * Sn + q * 32;
        #pragma unroll
        for (int j = 0; j < 8; ++j) {
            float4 o = {v[j*4]*inv, v[j*4+1]*inv, v[j*4+2]*inv, v[j*4+3]*inv};
            *(float4*)&dst[j * 4] = o;
        }
    }
    #pragma unroll
    for (int i = 0; i < 4; ++i) {
        int c = q * 4 + i;
        uint4 u;
        u.x = pkrn(v[i*8+0]*inv, v[i*8+1]*inv);
        u.y = pkrn(v[i*8+2]*inv, v[i*8+3]*inv);
        u.z = pkrn(v[i*8+4]*inv, v[i*8+5]*inv);
        u.w = pkrn(v[i*8+6]*inv, v[i*8+7]*inv);
        *(uint4*)&avs[r * 128 + (c ^ (r & 7)) * 8] = u;
    }
    // stage B (memT rows = d)
    #pragma unroll
    for (int j = 0; j < 4; ++j) {
        int idx = tid * 4 + j;
        int rB = idx >> 4, cB = idx & 15;
        *(short8*)&Bs[rB * 128 + (cB ^ (rB & 7)) * 8] =
            *(const short8*)&memTb[((long)b * Dn + ntb * 64 + rB) * Sn + cB * 8];
    }
    __syncthreads();

    // phase 2: c tile = avs @ Bs^T (K=128)
    const int wid = tid >> 6, lane = tid & 63;
    const int lm = lane & 15, lq = lane >> 4;
    const int wm = wid & 1, wn = wid >> 1;

    f32x4 acc[2][2];
    #pragma unroll
    for (int i = 0; i < 2; ++i)
        #pragma unroll
        for (int j = 0; j < 2; ++j) acc[i][j] = (f32x4){0.f, 0.f, 0.f, 0.f};

    #pragma unroll
    for (int kk = 0; kk < 4; ++kk) {
        const int p = (kk * 4 + lq) ^ (lm & 7);
        short8 a0 = *(const short8*)&avs[(wm * 32 + lm) * 128 + p * 8];
        short8 a1 = *(const short8*)&avs[(wm * 32 + 16 + lm) * 128 + p * 8];
        short8 b0 = *(const short8*)&Bs[(wn * 32 + lm) * 128 + p * 8];
        short8 b1 = *(const short8*)&Bs[(wn * 32 + 16 + lm) * 128 + p * 8];
        acc[0][0] = __builtin_amdgcn_mfma_f32_16x16x32_bf16(a0, b0, acc[0][0], 0, 0, 0);
        acc[0][1] = __builtin_amdgcn_mfma_f32_16x16x32_bf16(a0, b1, acc[0][1], 0, 0, 0);
        acc[1][0] = __builtin_amdgcn_mfma_f32_16x16x32_bf16(a1, b0, acc[1][0], 0, 0, 0);
        acc[1][1] = __builtin_amdgcn_mfma_f32_16x16x32_bf16(a1, b1, acc[1][1], 0, 0, 0);
    }
    #pragma unroll
    for (int mt = 0; mt < 2; ++mt)
        #pragma unroll
        for (int nt = 0; nt < 2; ++nt)
            #pragma unroll
            for (int rr = 0; rr < 4; ++rr) {
                long mrow = (long)b * Tn + mtb * 64 + wm * 32 + mt * 16 + lq * 4 + rr;
                int n = ntb * 64 + wn * 32 + nt * 16 + lm;
                concatb[mrow * 1024 + n] = f2bf(acc[mt][nt][rr]);
            }
}

// ---------------------------------------------------------------------------
extern "C" void kernel_launch(void* const* d_in, const int* in_sizes, int n_in,
                              void* d_out, int out_size, void* d_ws, size_t ws_size,
                              hipStream_t stream)
{
    (void)in_sizes; (void)n_in; (void)out_size; (void)ws_size;

    const float* input  = (const float*)d_in[0];
    const float* mem    = (const float*)d_in[1];
    const float* W_in   = (const float*)d_in[2];
    const float* W1     = (const float*)d_in[3];
    const float* b1     = (const float*)d_in[4];
    const float* W2     = (const float*)d_in[5];
    const float* b2     = (const float*)d_in[6];
    const float* w_mean = (const float*)d_in[7];
    const float* b_mean = (const float*)d_in[8];
    const float* w_var  = (const float*)d_in[9];
    const float* b_var  = (const float*)d_in[10];
    const float* W_out  = (const float*)d_in[11];

    float* out      = (float*)d_out;
    float* attn_out = out;
    float* av_out   = out + (long)Tn * Bn * Dn;
    float* mean_out = av_out + (long)Tn * Bn * Sn;
    float* var_out  = mean_out + (long)Bn * Tn * Sn;

    char* p = (char*)d_ws;
    unsigned short* inh   = (unsigned short*)p; p += 2097152;   // [2048][512]
    unsigned short* memh  = (unsigned short*)p; p += 2097152;   // contiguous after inh!
    unsigned short* inl   = (unsigned short*)p; p += 2097152;
    unsigned short* meml  = (unsigned short*)p; p += 2097152;
    unsigned short* winh  = (unsigned short*)p; p += 524288;
    unsigned short* winl  = (unsigned short*)p; p += 524288;
    unsigned short* w1b   = (unsigned short*)p; p += 204800;
    unsigned short* woutb = (unsigned short*)p; p += 1048576;
    unsigned short* w2b   = (unsigned short*)p; p += 28672;
    unsigned short* memTb = (unsigned short*)p; p += 2097152;
    unsigned short* hth   = (unsigned short*)p; p += 2097152;
    unsigned short* htl   = (unsigned short*)p; p += 2097152;
    float* ptps           = (float*)p;          p += 2097152;   // [4096][128]
    float* algn           = (float*)p;          p += 4194304;   // 4 partials
    unsigned short* concatb = (unsigned short*)p; p += 4194304;

    const long kstride = (long)Bn * Tn * Sn;

    // 0) conversions + mem transpose
    conv_trans<<<dim3(2930 + 256), 256, 0, stream>>>(
        input, mem, W_in, W1, W_out, W2,
        inh, inl, memh, meml, winh, winl, w1b, woutb, w2b, concatb, memTb);

    // 1) ht (split, hi/lo out) + pt/ps (padded ptps)   384 blocks
    gemm_ht_ptps<<<dim3(384), 256, 0, stream>>>(
        inh, inl, winh, winl, hth, htl, w1b, ptps, b1);

    // 2) align = ht @ mem^T, split, K-split x4   256 blocks
    mfma_gemm3<1, 0, 4, 0><<<dim3(2, 2, 64), 256, 0, stream>>>(
        hth, htl, memh, meml, algn, nullptr, nullptr, nullptr,
        Sn, Dn, Dn, Dn, Sn, (long)Tn * Dn, (long)Sn * Dn,
        (long)Tn * Sn, kstride);

    // 3) fused MLP (R6 variant)   2048 blocks
    mlp_mfma4<<<dim3(Tn / TT2, Bn * 2), 256, 0, stream>>>(
        ptps, w2b, b2, w_mean, b_mean, w_var, b_var, mean_out, var_out);

    // 4) fused softmax + c-GEMM (also writes av_out)   256 blocks
    softmax_c<<<dim3(8, 2, 16), 256, 0, stream>>>(
        algn, kstride, memTb, av_out, concatb);

    // 5) attn_h = tanh(concat @ W_out^T) -> (T,B,D)   256 blocks
    mfma_gemm3<0, 2, 0, 0><<<dim3(8, 32), 256, 0, stream>>>(
        concatb, nullptr, woutb, nullptr, attn_out, nullptr, nullptr, nullptr,
        Dn, 2 * Dn, 2 * Dn, 2 * Dn, Dn, 0L, 0L, 0L, 0L);
}

// Round 11
// 170.267 us; speedup vs baseline: 1.7333x; 1.0131x over previous
//
#include <hip/hip_runtime.h>
#include <hip/hip_bf16.h>
#include <math.h>

#define Bn 16
#define Tn 128
#define Sn 128
#define Dn 512
#define Hn 100
#define TT4 4

typedef short short8 __attribute__((ext_vector_type(8)));
typedef float f32x4 __attribute__((ext_vector_type(4)));
typedef unsigned short ushort4v __attribute__((ext_vector_type(4)));

__device__ __forceinline__ float softplus_f(float x) {
    return fmaxf(x, 0.0f) + __logf(1.0f + __expf(-fabsf(x)));
}
__device__ __forceinline__ unsigned short f2bf(float f) {
    unsigned u = __float_as_uint(f);
    unsigned r = u + 0x7FFFu + ((u >> 16) & 1u);
    return (unsigned short)(r >> 16);
}
__device__ __forceinline__ float bf2f(unsigned short h) {
    return __uint_as_float(((unsigned)h) << 16);
}
__device__ __forceinline__ unsigned pkrn(float a, float b) {
    __hip_bfloat162 h = __float22bfloat162_rn(float2{a, b});
    return *reinterpret_cast<unsigned*>(&h);
}
struct BfPair { unsigned short h, l; };
__device__ __forceinline__ BfPair split2(float x) {
    BfPair p;
    p.h = f2bf(x);
    p.l = f2bf(x - bf2f(p.h));
    return p;
}

// ---------------------------------------------------------------------------
// Fused conversion + mem transpose (blocks >= 2930 do the transpose).
// ---------------------------------------------------------------------------
__global__ __launch_bounds__(256)
void conv_trans(const float* __restrict__ input, const float* __restrict__ mem,
                const float* __restrict__ W_in, const float* __restrict__ W1,
                const float* __restrict__ W_out, const float* __restrict__ W2,
                unsigned short* __restrict__ inh, unsigned short* __restrict__ inl,
                unsigned short* __restrict__ memh, unsigned short* __restrict__ meml,
                unsigned short* __restrict__ winh, unsigned short* __restrict__ winl,
                unsigned short* __restrict__ w1b, unsigned short* __restrict__ woutb,
                unsigned short* __restrict__ w2b, unsigned short* __restrict__ concatb,
                unsigned short* __restrict__ memTb)
{
    __shared__ float tile[64][65];
    const int bx = blockIdx.x;
    if (bx >= 2930) {
        const int b2x = bx - 2930;
        const int d0 = (b2x & 7) * 64, s0 = ((b2x >> 3) & 1) * 64, b = b2x >> 4;
        const int tid = threadIdx.x;
        const int r = tid >> 2, cb = (tid & 3) * 16;
        const float* src = mem + ((long)b * Sn + s0 + r) * Dn + d0 + cb;
        #pragma unroll
        for (int j = 0; j < 4; ++j) {
            float4 v = *(const float4*)&src[j * 4];
            tile[r][cb + j * 4 + 0] = v.x;
            tile[r][cb + j * 4 + 1] = v.y;
            tile[r][cb + j * 4 + 2] = v.z;
            tile[r][cb + j * 4 + 3] = v.w;
        }
        __syncthreads();
        unsigned short* dst = memTb + ((long)b * Dn + d0 + r) * Sn + s0 + cb;
        #pragma unroll
        for (int j = 0; j < 4; ++j) {
            ushort4v q;
            q.x = f2bf(tile[cb + j * 4 + 0][r]);
            q.y = f2bf(tile[cb + j * 4 + 1][r]);
            q.z = f2bf(tile[cb + j * 4 + 2][r]);
            q.w = f2bf(tile[cb + j * 4 + 3][r]);
            *(ushort4v*)&dst[j * 4] = q;
        }
        return;
    }
    long gid = (long)bx * 1024 + (long)threadIdx.x * 4;
    if (gid < 1048576) {
        float4 v = *(const float4*)&input[gid];
        BfPair a = split2(v.x), b = split2(v.y), c = split2(v.z), d = split2(v.w);
        ushort4v h = {a.h, b.h, c.h, d.h};
        ushort4v l = {a.l, b.l, c.l, d.l};
        *(ushort4v*)&inh[gid] = h;
        *(ushort4v*)&inl[gid] = l;
        long row = gid >> 9; int col = (int)(gid & 511);
        *(ushort4v*)&concatb[row * 1024 + 512 + col] = h;
    } else if (gid < 2097152) {
        long e = gid - 1048576;
        float4 v = *(const float4*)&mem[e];
        BfPair a = split2(v.x), b = split2(v.y), c = split2(v.z), d = split2(v.w);
        ushort4v h = {a.h, b.h, c.h, d.h};
        ushort4v l = {a.l, b.l, c.l, d.l};
        *(ushort4v*)&memh[e] = h;
        *(ushort4v*)&meml[e] = l;
    } else if (gid < 2359296) {
        long e = gid - 2097152;
        float4 v = *(const float4*)&W_in[e];
        BfPair a = split2(v.x), b = split2(v.y), c = split2(v.z), d = split2(v.w);
        ushort4v h = {a.h, b.h, c.h, d.h};
        ushort4v l = {a.l, b.l, c.l, d.l};
        *(ushort4v*)&winh[e] = h;
        *(ushort4v*)&winl[e] = l;
    } else if (gid < 2461696) {
        long e = gid - 2359296;
        float4 v = *(const float4*)&W1[e];
        ushort4v h = {f2bf(v.x), f2bf(v.y), f2bf(v.z), f2bf(v.w)};
        *(ushort4v*)&w1b[e] = h;
    } else if (gid < 2985984) {
        long e = gid - 2461696;
        float4 v = *(const float4*)&W_out[e];
        ushort4v h = {f2bf(v.x), f2bf(v.y), f2bf(v.z), f2bf(v.w)};
        *(ushort4v*)&woutb[e] = h;
    } else {
        long e = gid - 2985984;           // [112][128] padded W2
        int n = (int)(e >> 7), k = (int)(e & 127);
        ushort4v h;
        #pragma unroll
        for (int j = 0; j < 4; ++j) {
            int kj = k + j;
            float val = (n < Hn && kj < Hn) ? W2[n * Hn + kj] : 0.0f;
            h[j] = f2bf(val);
        }
        *(ushort4v*)&w2b[n * 128 + k] = h;
    }
}

// ---------------------------------------------------------------------------
// 64x64-tile bf16 MFMA GEMM body (NT). BK=64, 256 thr = 4 waves (2x2).
// Register-prefetch double-buffered K-loop.
// ---------------------------------------------------------------------------
template<int SPLIT, int EPI, int KSPLIT, int BSEL>
__device__ __forceinline__
void gemm_body(int bx, int by, int bz_in, int upperThresh,
               const unsigned short* __restrict__ Ah, const unsigned short* __restrict__ Al,
               const unsigned short* __restrict__ Bh, const unsigned short* __restrict__ Bl,
               float* __restrict__ C, unsigned short* __restrict__ Cb,
               unsigned short* __restrict__ Cb2, const float* __restrict__ bias,
               int N, int K, int lda, int ldb, int ldc,
               long sA, long sB, long sC, long sKC,
               unsigned short* As_, unsigned short* Bs_)
{
    unsigned short* Asl = As_ + 4096;
    unsigned short* Bsl = Bs_ + 4096;

    const int tid = threadIdx.x;
    const int n0 = bx * 64;
    const long m0 = (long)by * 64;
    int bz = bz_in, kh = 0;
    if (KSPLIT) { bz = bz_in & 15; kh = bz_in >> 4; }
    Ah += (long)bz * sA;
    Bh += (long)bz * sB;
    if (SPLIT) { Al += (long)bz * sA; Bl += (long)bz * sB; }
    const bool upperB = BSEL && (by >= upperThresh);
    if (upperB) Bh += BSEL;

    const int kbeg = KSPLIT ? kh * (K / KSPLIT) : 0;
    const int kend = KSPLIT ? kbeg + (K / KSPLIT) : K;

    const int wid = tid >> 6, lane = tid & 63;
    const int lm = lane & 15, lq = lane >> 4;
    const int wm = wid & 1, wn = wid >> 1;

    const int sr = tid >> 2;
    const int sc = (tid & 3) * 2;
    const bool bok = (n0 + sr) < N;

    f32x4 acc[2][2];
    #pragma unroll
    for (int i = 0; i < 2; ++i)
        #pragma unroll
        for (int j = 0; j < 2; ++j)
            acc[i][j] = (f32x4){0.f, 0.f, 0.f, 0.f};

    short8 pA[2], pB[2], pAl[2], pBl[2];
    const short8 zz = {0, 0, 0, 0, 0, 0, 0, 0};

    #pragma unroll
    for (int i = 0; i < 2; ++i) {
        int c = sc + i;
        pA[i] = *(const short8*)&Ah[(m0 + sr) * lda + kbeg + c * 8];
        if (SPLIT) pAl[i] = *(const short8*)&Al[(m0 + sr) * lda + kbeg + c * 8];
        pB[i] = bok ? *(const short8*)&Bh[(long)(n0 + sr) * ldb + kbeg + c * 8] : zz;
        if (SPLIT) pBl[i] = bok ? *(const short8*)&Bl[(long)(n0 + sr) * ldb + kbeg + c * 8] : zz;
    }

    for (int k0 = kbeg; k0 < kend; k0 += 64) {
        __syncthreads();
        #pragma unroll
        for (int i = 0; i < 2; ++i) {
            int c = sc + i, p = c ^ (sr & 7);
            *(short8*)&As_[sr * 64 + p * 8] = pA[i];
            *(short8*)&Bs_[sr * 64 + p * 8] = pB[i];
            if (SPLIT) {
                *(short8*)&Asl[sr * 64 + p * 8] = pAl[i];
                *(short8*)&Bsl[sr * 64 + p * 8] = pBl[i];
            }
        }
        __syncthreads();
        if (k0 + 64 < kend) {
            const int kn = k0 + 64;
            #pragma unroll
            for (int i = 0; i < 2; ++i) {
                int c = sc + i;
                pA[i] = *(const short8*)&Ah[(m0 + sr) * lda + kn + c * 8];
                if (SPLIT) pAl[i] = *(const short8*)&Al[(m0 + sr) * lda + kn + c * 8];
                pB[i] = bok ? *(const short8*)&Bh[(long)(n0 + sr) * ldb + kn + c * 8] : zz;
                if (SPLIT) pBl[i] = bok ? *(const short8*)&Bl[(long)(n0 + sr) * ldb + kn + c * 8] : zz;
            }
        }
        #pragma unroll
        for (int kst = 0; kst < 2; ++kst) {
            short8 a[2], b[2], a2[2], b2r[2];
            const int pp = (kst * 4 + lq) ^ (lm & 7);
            #pragma unroll
            for (int mt = 0; mt < 2; ++mt) {
                int row = wm * 32 + mt * 16 + lm;
                a[mt] = *(const short8*)&As_[row * 64 + pp * 8];
                if (SPLIT) a2[mt] = *(const short8*)&Asl[row * 64 + pp * 8];
            }
            #pragma unroll
            for (int nt = 0; nt < 2; ++nt) {
                int row = wn * 32 + nt * 16 + lm;
                b[nt] = *(const short8*)&Bs_[row * 64 + pp * 8];
                if (SPLIT) b2r[nt] = *(const short8*)&Bsl[row * 64 + pp * 8];
            }
            #pragma unroll
            for (int mt = 0; mt < 2; ++mt)
                #pragma unroll
                for (int nt = 0; nt < 2; ++nt) {
                    if (SPLIT) {
                        acc[mt][nt] = __builtin_amdgcn_mfma_f32_16x16x32_bf16(
                            a2[mt], b[nt], acc[mt][nt], 0, 0, 0);
                        acc[mt][nt] = __builtin_amdgcn_mfma_f32_16x16x32_bf16(
                            a[mt], b2r[nt], acc[mt][nt], 0, 0, 0);
                    }
                    acc[mt][nt] = __builtin_amdgcn_mfma_f32_16x16x32_bf16(
                        a[mt], b[nt], acc[mt][nt], 0, 0, 0);
                }
        }
    }

    #pragma unroll
    for (int mt = 0; mt < 2; ++mt)
        #pragma unroll
        for (int nt = 0; nt < 2; ++nt)
            #pragma unroll
            for (int r = 0; r < 4; ++r) {
                long m = m0 + wm * 32 + mt * 16 + lq * 4 + r;
                int n = n0 + wn * 32 + nt * 16 + lm;
                float v = acc[mt][nt][r];
                if (EPI == 0) {
                    if (n < N)
                        C[(long)bz * sC + (long)kh * sKC + m * ldc + n] = v;
                } else if (EPI == 1) {
                    unsigned short h = f2bf(v);
                    Cb[m * ldc + n] = h;
                    Cb2[m * ldc + n] = f2bf(v - bf2f(h));
                } else if (EPI == 2) {
                    long bb = m >> 7, tt = m & 127;
                    C[tt * (Bn * Dn) + bb * Dn + n] = tanhf(v);
                } else if (EPI == 3) {
                    Cb[(long)bz * sC + m * ldc + n] = f2bf(v);
                } else {
                    float bb = (!upperB && n < Hn) ? bias[n] : 0.f;
                    C[m * ldc + n] = v + bb;
                }
            }
}

template<int SPLIT, int EPI, int KSPLIT, int BSEL>
__global__ __launch_bounds__(256)
void mfma_gemm3(const unsigned short* __restrict__ Ah, const unsigned short* __restrict__ Al,
                const unsigned short* __restrict__ Bh, const unsigned short* __restrict__ Bl,
                float* __restrict__ C, unsigned short* __restrict__ Cb,
                unsigned short* __restrict__ Cb2, const float* __restrict__ bias,
                int N, int K, int lda, int ldb, int ldc,
                long sA, long sB, long sC, long sKC)
{
    __shared__ __align__(16) unsigned short As_[(SPLIT ? 2 : 1) * 4096];
    __shared__ __align__(16) unsigned short Bs_[(SPLIT ? 2 : 1) * 4096];
    gemm_body<SPLIT, EPI, KSPLIT, BSEL>(blockIdx.x, blockIdx.y, blockIdx.z,
        (int)(gridDim.y >> 1), Ah, Al, Bh, Bl, C, Cb, Cb2, bias,
        N, K, lda, ldb, ldc, sA, sB, sC, sKC, As_, Bs_);
}

// ---------------------------------------------------------------------------
// Merged independent GEMMs: blocks 0..255 = ht (split), 256..383 = pt+ps.
// ---------------------------------------------------------------------------
__global__ __launch_bounds__(256)
void gemm_ht_ptps(const unsigned short* __restrict__ inh, const unsigned short* __restrict__ inl,
                  const unsigned short* __restrict__ winh, const unsigned short* __restrict__ winl,
                  unsigned short* __restrict__ hth, unsigned short* __restrict__ htl,
                  const unsigned short* __restrict__ w1b, float* __restrict__ ptps,
                  const float* __restrict__ b1)
{
    __shared__ __align__(16) unsigned short As_[8192];
    __shared__ __align__(16) unsigned short Bs_[8192];
    const int id = blockIdx.x;
    if (id < 256) {
        gemm_body<1, 1, 0, 0>(id & 7, id >> 3, 0, 0,
            inh, inl, winh, winl, nullptr, hth, htl, nullptr,
            Dn, Dn, Dn, Dn, Dn, 0L, 0L, 0L, 0L, As_, Bs_);
    } else {
        const int j = id - 256;
        gemm_body<0, 4, 0, 512>(j & 1, j >> 1, 0, 32,
            inh, nullptr, w1b, nullptr, ptps, nullptr, nullptr, b1,
            Hn, Dn, Dn, 2 * Dn, 128, 0L, 0L, 0L, 0L, As_, Bs_);
    }
}

// ---------------------------------------------------------------------------
// MLP body (R6/R10 mlp_mfma4 structure, TT=4). smem layout:
//   h1s[64*128] us (16384) | w2s[112*128] us (28672) | ptl[4][140] f |
//   b2p[112] | wmp[112] | wvp[112]   -> total 48640 B
// ---------------------------------------------------------------------------
__device__ __forceinline__
void mlp_body(int tg, int yid, char* smem,
              const float* __restrict__ ptps, const unsigned short* __restrict__ w2b,
              const float* __restrict__ b2,
              const float* __restrict__ w_mean, const float* __restrict__ b_mean,
              const float* __restrict__ w_var, const float* __restrict__ b_var,
              float* __restrict__ mean_out, float* __restrict__ var_out)
{
    unsigned short* h1s = (unsigned short*)smem;
    unsigned short* w2s = (unsigned short*)(smem + 16384);
    float (*ptl)[140]   = (float(*)[140])(smem + 45056);
    float* b2p          = (float*)(smem + 47296);
    float* wmp          = (float*)(smem + 47744);
    float* wvp          = (float*)(smem + 48192);

    const int b  = yid >> 1;
    const int s0 = (yid & 1) * 64;
    const int tid = threadIdx.x;

    // stage w2 (swizzled)
    #pragma unroll
    for (int i0 = 0; i0 < 7; ++i0) {
        int i = tid + i0 * 256;
        int r_ = i >> 4, c_ = i & 15;
        *(short8*)&w2s[r_ * 128 + (c_ ^ (r_ & 7)) * 8] = *(const short8*)&w2b[i * 8];
    }
    // stage pt rows (4 x 128, bank-offset layout)
    #pragma unroll
    for (int j = 0; j < 2; ++j) {
        int i = tid + j * 256;
        int tt = i >> 7, c = i & 127;
        ptl[tt][c + 4 * (c >> 5)] =
            ptps[((long)b * Tn + tg * TT4 + tt) * 128 + c];
    }
    if (tid < 112) {
        b2p[tid] = (tid < Hn) ? b2[tid] : 0.f;
        wmp[tid] = (tid < Hn) ? w_mean[tid] : 0.f;
        wvp[tid] = (tid < Hn) ? w_var[tid] : 0.f;
    }

    // ps tile -> registers: row r, strided chunks c = cb + 4*i (8 cols each)
    const int r = tid >> 2, cb = tid & 3;
    float psreg[4][8];
    {
        const float* psrow = ptps + (long)(2048 + b * Sn + s0 + r) * 128;
        #pragma unroll
        for (int i = 0; i < 4; ++i) {
            int col = (cb + 4 * i) * 8;
            *(float4*)&psreg[i][0] = *(const float4*)&psrow[col];
            *(float4*)&psreg[i][4] = *(const float4*)&psrow[col + 4];
        }
    }
    __syncthreads();

    const int wid = tid >> 6, lane = tid & 63;
    const int lm = lane & 15, lq = lane >> 4;
    const float bm = b_mean[0], bv = b_var[0];

    for (int t = 0; t < TT4; ++t) {
        #pragma unroll
        for (int i = 0; i < 4; ++i) {
            const int c = cb + 4 * i;
            const int col = c * 8;
            const int base = col + 4 * (col >> 5);
            float4 pa = *(const float4*)&ptl[t][base];
            float4 pb = *(const float4*)&ptl[t][base + 4];
            float x0 = softplus_f(psreg[i][0] + pa.x);
            float x1 = softplus_f(psreg[i][1] + pa.y);
            float x2 = softplus_f(psreg[i][2] + pa.z);
            float x3 = softplus_f(psreg[i][3] + pa.w);
            float x4 = softplus_f(psreg[i][4] + pb.x);
            float x5 = softplus_f(psreg[i][5] + pb.y);
            float x6 = softplus_f(psreg[i][6] + pb.z);
            float x7 = softplus_f(psreg[i][7] + pb.w);
            uint4 u;
            u.x = pkrn(x0, x1); u.y = pkrn(x2, x3);
            u.z = pkrn(x4, x5); u.w = pkrn(x6, x7);
            *(uint4*)&h1s[r * 128 + (c ^ (r & 7)) * 8] = u;
        }
        __syncthreads();

        f32x4 acc[7];
        #pragma unroll
        for (int j = 0; j < 7; ++j) acc[j] = (f32x4){0.f, 0.f, 0.f, 0.f};
        #pragma unroll
        for (int ks = 0; ks < 4; ++ks) {
            const int p = (ks * 4 + lq) ^ (lm & 7);
            short8 a = *(const short8*)&h1s[(wid * 16 + lm) * 128 + p * 8];
            #pragma unroll
            for (int nt = 0; nt < 7; ++nt) {
                short8 bf = *(const short8*)&w2s[(nt * 16 + lm) * 128 + p * 8];
                acc[nt] = __builtin_amdgcn_mfma_f32_16x16x32_bf16(a, bf, acc[nt], 0, 0, 0);
            }
        }

        float sM[4] = {}, sV[4] = {};
        #pragma unroll
        for (int nt = 0; nt < 7; ++nt) {
            int g = nt * 16 + lm;
            float bg = b2p[g], wm_ = wmp[g], wv_ = wvp[g];
            #pragma unroll
            for (int rr = 0; rr < 4; ++rr) {
                float h2 = softplus_f(acc[nt][rr] + bg);
                sM[rr] = fmaf(h2, wm_, sM[rr]);
                sV[rr] = fmaf(h2, wv_, sV[rr]);
            }
        }
        #pragma unroll
        for (int off = 1; off < 16; off <<= 1)
            #pragma unroll
            for (int rr = 0; rr < 4; ++rr) {
                sM[rr] += __shfl_xor(sM[rr], off);
                sV[rr] += __shfl_xor(sV[rr], off);
            }
        if (lm == 0) {
            const long base = ((long)b * Tn + tg * TT4 + t) * Sn + s0;
            #pragma unroll
            for (int rr = 0; rr < 4; ++rr) {
                int row = wid * 16 + lq * 4 + rr;
                mean_out[base + row] = softplus_f(sM[rr] + bm);
                var_out[base + row]  = softplus_f(sV[rr] + bv);
            }
        }
        __syncthreads();
    }
}

// ---------------------------------------------------------------------------
// softmax + c-GEMM body. smem: avs[64*128] us | Bs[64*128] us  (32768 B)
// ---------------------------------------------------------------------------
__device__ __forceinline__
void softmax_c_body(int ntb, int mtb, int b, char* smem,
                    const float* __restrict__ algn, long kstride,
                    const unsigned short* __restrict__ memTb,
                    float* __restrict__ av_out, unsigned short* __restrict__ concatb)
{
    unsigned short* avs = (unsigned short*)smem;
    unsigned short* Bs  = (unsigned short*)(smem + 16384);

    const int tid = threadIdx.x;
    const int r = tid >> 2, q = tid & 3;

    float v[32];
    {
        const float* arow = algn + ((long)b * Tn + mtb * 64 + r) * Sn + q * 32;
        #pragma unroll
        for (int j = 0; j < 8; ++j) {
            float4 a0 = *(const float4*)&arow[j * 4];
            float4 a1 = *(const float4*)&arow[j * 4 + kstride];
            float4 a2 = *(const float4*)&arow[j * 4 + 2 * kstride];
            float4 a3 = *(const float4*)&arow[j * 4 + 3 * kstride];
            v[j * 4 + 0] = a0.x + a1.x + a2.x + a3.x;
            v[j * 4 + 1] = a0.y + a1.y + a2.y + a3.y;
            v[j * 4 + 2] = a0.z + a1.z + a2.z + a3.z;
            v[j * 4 + 3] = a0.w + a1.w + a2.w + a3.w;
        }
    }
    float mx = v[0];
    #pragma unroll
    for (int i = 1; i < 32; ++i) mx = fmaxf(mx, v[i]);
    mx = fmaxf(mx, __shfl_xor(mx, 1));
    mx = fmaxf(mx, __shfl_xor(mx, 2));
    float sum = 0.f;
    #pragma unroll
    for (int i = 0; i < 32; ++i) { v[i] = __expf(v[i] - mx); sum += v[i]; }
    sum += __shfl_xor(sum, 1);
    sum += __shfl_xor(sum, 2);
    const float inv = 1.0f / sum;

    if (ntb == 0) {
        float* dst = av_out + (long)(mtb * 64 + r) * (Bn * Sn) + b * Sn + q * 32;
        #pragma unroll
        for (int j = 0; j < 8; ++j) {
            float4 o = {v[j*4]*inv, v[j*4+1]*inv, v[j*4+2]*inv, v[j*4+3]*inv};
            *(float4*)&dst[j * 4] = o;
        }
    }
    #pragma unroll
    for (int i = 0; i < 4; ++i) {
        int c = q * 4 + i;
        uint4 u;
        u.x = pkrn(v[i*8+0]*inv, v[i*8+1]*inv);
        u.y = pkrn(v[i*8+2]*inv, v[i*8+3]*inv);
        u.z = pkrn(v[i*8+4]*inv, v[i*8+5]*inv);
        u.w = pkrn(v[i*8+6]*inv, v[i*8+7]*inv);
        *(uint4*)&avs[r * 128 + (c ^ (r & 7)) * 8] = u;
    }
    #pragma unroll
    for (int j = 0; j < 4; ++j) {
        int idx = tid * 4 + j;
        int rB = idx >> 4, cB = idx & 15;
        *(short8*)&Bs[rB * 128 + (cB ^ (rB & 7)) * 8] =
            *(const short8*)&memTb[((long)b * Dn + ntb * 64 + rB) * Sn + cB * 8];
    }
    __syncthreads();

    const int wid = tid >> 6, lane = tid & 63;
    const int lm = lane & 15, lq = lane >> 4;
    const int wm = wid & 1, wn = wid >> 1;

    f32x4 acc[2][2];
    #pragma unroll
    for (int i = 0; i < 2; ++i)
        #pragma unroll
        for (int j = 0; j < 2; ++j) acc[i][j] = (f32x4){0.f, 0.f, 0.f, 0.f};

    #pragma unroll
    for (int kk = 0; kk < 4; ++kk) {
        const int p = (kk * 4 + lq) ^ (lm & 7);
        short8 a0 = *(const short8*)&avs[(wm * 32 + lm) * 128 + p * 8];
        short8 a1 = *(const short8*)&avs[(wm * 32 + 16 + lm) * 128 + p * 8];
        short8 b0 = *(const short8*)&Bs[(wn * 32 + lm) * 128 + p * 8];
        short8 b1 = *(const short8*)&Bs[(wn * 32 + 16 + lm) * 128 + p * 8];
        acc[0][0] = __builtin_amdgcn_mfma_f32_16x16x32_bf16(a0, b0, acc[0][0], 0, 0, 0);
        acc[0][1] = __builtin_amdgcn_mfma_f32_16x16x32_bf16(a0, b1, acc[0][1], 0, 0, 0);
        acc[1][0] = __builtin_amdgcn_mfma_f32_16x16x32_bf16(a1, b0, acc[1][0], 0, 0, 0);
        acc[1][1] = __builtin_amdgcn_mfma_f32_16x16x32_bf16(a1, b1, acc[1][1], 0, 0, 0);
    }
    #pragma unroll
    for (int mt = 0; mt < 2; ++mt)
        #pragma unroll
        for (int nt = 0; nt < 2; ++nt)
            #pragma unroll
            for (int rr = 0; rr < 4; ++rr) {
                long mrow = (long)b * Tn + mtb * 64 + wm * 32 + mt * 16 + lq * 4 + rr;
                int n = ntb * 64 + wn * 32 + nt * 16 + lm;
                concatb[mrow * 1024 + n] = f2bf(acc[mt][nt][rr]);
            }
}

// ---------------------------------------------------------------------------
// Launch D: softmax_c (blocks 0..255) + mlp blocks 0..511 (yid 0..15).
// ---------------------------------------------------------------------------
__global__ __launch_bounds__(256)
void sm_mlp(const float* __restrict__ algn, long kstride,
            const unsigned short* __restrict__ memTb,
            float* __restrict__ av_out, unsigned short* __restrict__ concatb,
            const float* __restrict__ ptps, const unsigned short* __restrict__ w2b,
            const float* __restrict__ b2,
            const float* __restrict__ w_mean, const float* __restrict__ b_mean,
            const float* __restrict__ w_var, const float* __restrict__ b_var,
            float* __restrict__ mean_out, float* __restrict__ var_out)
{
    __shared__ __align__(16) char smem[48640];
    const int id = blockIdx.x;
    if (id < 256) {
        softmax_c_body(id & 7, (id >> 3) & 1, id >> 4, smem,
                       algn, kstride, memTb, av_out, concatb);
    } else {
        const int mid = id - 256;
        mlp_body(mid & 31, mid >> 5, smem,
                 ptps, w2b, b2, w_mean, b_mean, w_var, b_var, mean_out, var_out);
    }
}

// ---------------------------------------------------------------------------
// Launch E: attn tanh-GEMM (blocks 0..255) + mlp blocks 512..1023 (yid 16..31).
// ---------------------------------------------------------------------------
__global__ __launch_bounds__(256)
void attn_mlp(const unsigned short* __restrict__ concatb,
              const unsigned short* __restrict__ woutb,
              float* __restrict__ attn_out,
              const float* __restrict__ ptps, const unsigned short* __restrict__ w2b,
              const float* __restrict__ b2,
              const float* __restrict__ w_mean, const float* __restrict__ b_mean,
              const float* __restrict__ w_var, const float* __restrict__ b_var,
              float* __restrict__ mean_out, float* __restrict__ var_out)
{
    __shared__ __align__(16) char smem[48640];
    const int id = blockIdx.x;
    if (id < 256) {
        gemm_body<0, 2, 0, 0>(id & 7, id >> 3, 0, 0,
            concatb, nullptr, woutb, nullptr, attn_out, nullptr, nullptr, nullptr,
            Dn, 2 * Dn, 2 * Dn, 2 * Dn, Dn, 0L, 0L, 0L, 0L,
            (unsigned short*)smem, (unsigned short*)(smem + 8192));
    } else {
        const int mid = id - 256;
        mlp_body(mid & 31, 16 + (mid >> 5), smem,
                 ptps, w2b, b2, w_mean, b_mean, w_var, b_var, mean_out, var_out);
    }
}

// ---------------------------------------------------------------------------
extern "C" void kernel_launch(void* const* d_in, const int* in_sizes, int n_in,
                              void* d_out, int out_size, void* d_ws, size_t ws_size,
                              hipStream_t stream)
{
    (void)in_sizes; (void)n_in; (void)out_size; (void)ws_size;

    const float* input  = (const float*)d_in[0];
    const float* mem    = (const float*)d_in[1];
    const float* W_in   = (const float*)d_in[2];
    const float* W1     = (const float*)d_in[3];
    const float* b1     = (const float*)d_in[4];
    const float* W2     = (const float*)d_in[5];
    const float* b2     = (const float*)d_in[6];
    const float* w_mean = (const float*)d_in[7];
    const float* b_mean = (const float*)d_in[8];
    const float* w_var  = (const float*)d_in[9];
    const float* b_var  = (const float*)d_in[10];
    const float* W_out  = (const float*)d_in[11];

    float* out      = (float*)d_out;
    float* attn_out = out;
    float* av_out   = out + (long)Tn * Bn * Dn;
    float* mean_out = av_out + (long)Tn * Bn * Sn;
    float* var_out  = mean_out + (long)Bn * Tn * Sn;

    char* p = (char*)d_ws;
    unsigned short* inh   = (unsigned short*)p; p += 2097152;   // [2048][512]
    unsigned short* memh  = (unsigned short*)p; p += 2097152;   // contiguous after inh!
    unsigned short* inl   = (unsigned short*)p; p += 2097152;
    unsigned short* meml  = (unsigned short*)p; p += 2097152;
    unsigned short* winh  = (unsigned short*)p; p += 524288;
    unsigned short* winl  = (unsigned short*)p; p += 524288;
    unsigned short* w1b   = (unsigned short*)p; p += 204800;
    unsigned short* woutb = (unsigned short*)p; p += 1048576;
    unsigned short* w2b   = (unsigned short*)p; p += 28672;
    unsigned short* memTb = (unsigned short*)p; p += 2097152;
    unsigned short* hth   = (unsigned short*)p; p += 2097152;
    unsigned short* htl   = (unsigned short*)p; p += 2097152;
    float* ptps           = (float*)p;          p += 2097152;   // [4096][128]
    float* algn           = (float*)p;          p += 4194304;   // 4 partials
    unsigned short* concatb = (unsigned short*)p; p += 4194304;

    const long kstride = (long)Bn * Tn * Sn;

    // 0) conversions + mem transpose
    conv_trans<<<dim3(2930 + 256), 256, 0, stream>>>(
        input, mem, W_in, W1, W_out, W2,
        inh, inl, memh, meml, winh, winl, w1b, woutb, w2b, concatb, memTb);

    // 1) ht (split, hi/lo out) + pt/ps (padded ptps)   384 blocks
    gemm_ht_ptps<<<dim3(384), 256, 0, stream>>>(
        inh, inl, winh, winl, hth, htl, w1b, ptps, b1);

    // 2) align = ht @ mem^T, split, K-split x4   256 blocks
    mfma_gemm3<1, 0, 4, 0><<<dim3(2, 2, 64), 256, 0, stream>>>(
        hth, htl, memh, meml, algn, nullptr, nullptr, nullptr,
        Sn, Dn, Dn, Dn, Sn, (long)Tn * Dn, (long)Sn * Dn,
        (long)Tn * Sn, kstride);

    // 3) softmax + c-GEMM (256) + mlp half 1 (512)   768 blocks
    sm_mlp<<<dim3(768), 256, 0, stream>>>(
        algn, kstride, memTb, av_out, concatb,
        ptps, w2b, b2, w_mean, b_mean, w_var, b_var, mean_out, var_out);

    // 4) attn tanh-GEMM (256) + mlp half 2 (512)   768 blocks
    attn_mlp<<<dim3(768), 256, 0, stream>>>(
        concatb, woutb, attn_out,
        ptps, w2b, b2, w_mean, b_mean, w_var, b_var, mean_out, var_out);
}